// Round 1
// baseline (1647.701 us; speedup 1.0000x reference)
//
#include <hip/hip_runtime.h>
#include <math.h>

// Problem constants
#define LSEQ 2048
#define DMODEL 1024
#define DINNER 2048
#define NHEADS 32
#define HEADDIM 64
#define DSTATE 64
#define CONVDIM 2176   // DINNER + 2*DSTATE
#define DPROJ 4256     // 2*DINNER + 2*DSTATE + NHEADS
#define FFNHID 3072

__device__ __forceinline__ float siluf(float x){ return x / (1.0f + expf(-x)); }

// valid for blockDim.x == 256 (4 waves); returns full sum to all threads
__device__ __forceinline__ float block_reduce_sum_256(float v){
  #pragma unroll
  for (int o = 32; o > 0; o >>= 1) v += __shfl_down(v, o, 64);
  __shared__ float sh[4];
  int lane = threadIdx.x & 63;
  int w = threadIdx.x >> 6;
  if (lane == 0) sh[w] = v;
  __syncthreads();
  return sh[0] + sh[1] + sh[2] + sh[3];
}

// x_res = rm0*x + rm1*x0 ; u = rms(x_res)*ssm_norm_w
__global__ __launch_bounds__(256) void k_mix_rms(
    const float* __restrict__ x, const float* __restrict__ x0,
    const float* __restrict__ rm, const float* __restrict__ nw,
    float* __restrict__ xres, float* __restrict__ u)
{
  int row = blockIdx.x, tid = threadIdx.x;
  const float* xr  = x  + (size_t)row * DMODEL;
  const float* x0r = x0 + (size_t)row * DMODEL;
  float v[4]; float ss = 0.f;
  #pragma unroll
  for (int i = 0; i < 4; ++i){
    int d = tid + i * 256;
    float a = rm[d] * xr[d] + rm[DMODEL + d] * x0r[d];
    v[i] = a; ss += a * a;
    xres[(size_t)row * DMODEL + d] = a;
  }
  ss = block_reduce_sum_256(ss);
  float inv = rsqrtf(ss / (float)DMODEL + 1e-6f);
  #pragma unroll
  for (int i = 0; i < 4; ++i){
    int d = tid + i * 256;
    u[(size_t)row * DMODEL + d] = v[i] * inv * nw[d];
  }
}

// C[M,N] = A[M,K] @ W[N,K]^T   (fp32, 64x64 tile, BK=16, 4x4 per thread)
// Requires: M % 64 == 0, K % 16 == 0. N may be ragged (guarded).
__global__ __launch_bounds__(256) void k_gemm(
    const float* __restrict__ A, const float* __restrict__ W,
    float* __restrict__ C, int M, int N, int K)
{
  __shared__ float As[16][64];
  __shared__ float Ws[16][64];
  int bm = blockIdx.y * 64, bn = blockIdx.x * 64;
  int tid = threadIdx.x;
  int lr = tid >> 2;          // 0..63
  int lc = (tid & 3) * 4;     // 0,4,8,12
  int tm = (tid >> 4) * 4, tn = (tid & 15) * 4;
  float acc[4][4] = {{0.f}};
  for (int k0 = 0; k0 < K; k0 += 16){
    float4 av = *(const float4*)(A + (size_t)(bm + lr) * K + k0 + lc);
    float4 wv = make_float4(0.f,0.f,0.f,0.f);
    if (bn + lr < N) wv = *(const float4*)(W + (size_t)(bn + lr) * K + k0 + lc);
    As[lc+0][lr] = av.x; As[lc+1][lr] = av.y; As[lc+2][lr] = av.z; As[lc+3][lr] = av.w;
    Ws[lc+0][lr] = wv.x; Ws[lc+1][lr] = wv.y; Ws[lc+2][lr] = wv.z; Ws[lc+3][lr] = wv.w;
    __syncthreads();
    #pragma unroll
    for (int kk = 0; kk < 16; ++kk){
      float4 a = *(const float4*)&As[kk][tm];
      float4 b = *(const float4*)&Ws[kk][tn];
      float ar[4] = {a.x,a.y,a.z,a.w};
      float br[4] = {b.x,b.y,b.z,b.w};
      #pragma unroll
      for (int i = 0; i < 4; ++i)
        #pragma unroll
        for (int j = 0; j < 4; ++j)
          acc[i][j] = fmaf(ar[i], br[j], acc[i][j]);
    }
    __syncthreads();
  }
  #pragma unroll
  for (int i = 0; i < 4; ++i){
    int row = bm + tm + i;
    #pragma unroll
    for (int j = 0; j < 4; ++j){
      int col = bn + tn + j;
      if (col < N) C[(size_t)row * N + col] = acc[i][j];
    }
  }
}

// causal depthwise conv width 4 over zx columns [DINNER, DINNER+CONVDIM) + bias + silu
__global__ __launch_bounds__(256) void k_conv(
    const float* __restrict__ zx, const float* __restrict__ cw,
    const float* __restrict__ cb, float* __restrict__ xbc)
{
  int idx = blockIdx.x * 256 + threadIdx.x;
  if (idx >= LSEQ * CONVDIM) return;
  int l = idx / CONVDIM, c = idx - l * CONVDIM;
  float acc = cb[c];
  #pragma unroll
  for (int k = 0; k < 4; ++k){
    int t = l + k - 3;
    if (t >= 0) acc = fmaf(zx[(size_t)t * DPROJ + DINNER + c], cw[c*4 + k], acc);
  }
  xbc[idx] = siluf(acc);
}

// dt = softplus(raw + dt_bias); dA = exp(-exp(A_log)*dt)
__global__ __launch_bounds__(256) void k_dt(
    const float* __restrict__ zx, const float* __restrict__ dtb,
    const float* __restrict__ alog, float* __restrict__ dt, float* __restrict__ dA)
{
  int idx = blockIdx.x * 256 + threadIdx.x;
  if (idx >= LSEQ * NHEADS) return;
  int h = idx & (NHEADS - 1);
  int l = idx >> 5;
  float raw = zx[(size_t)l * DPROJ + DINNER + CONVDIM + h] + dtb[h];
  float d = (raw > 20.f) ? raw : log1pf(expf(raw));
  dt[idx] = d;
  dA[idx] = expf(-expf(alog[h]) * d);
}

// sequential selective scan; one block per head; thread owns (p = tid>>2, 16 states)
__global__ __launch_bounds__(256) void k_scan(
    const float* __restrict__ xbc, const float* __restrict__ dt,
    const float* __restrict__ dA, const float* __restrict__ Dp,
    float* __restrict__ y)
{
  __shared__ float sX[64][64];
  __shared__ float sB[64][64];
  __shared__ float sC[64][64];
  __shared__ float sdA[64], sdt[64];
  int head = blockIdx.x;
  int tid = threadIdx.x;
  int p = tid >> 2, nq = tid & 3, n0 = nq * 16;
  float h[16];
  #pragma unroll
  for (int j = 0; j < 16; ++j) h[j] = 0.f;
  float Dh = Dp[head];
  for (int t0 = 0; t0 < LSEQ; t0 += 64){
    __syncthreads();
    for (int i = tid; i < 4096; i += 256){
      int t = i >> 6, c = i & 63;
      size_t rb = (size_t)(t0 + t) * CONVDIM;
      sX[t][c] = xbc[rb + head * HEADDIM + c];
      sB[t][c] = xbc[rb + DINNER + c];
      sC[t][c] = xbc[rb + DINNER + DSTATE + c];
    }
    if (tid < 64){
      sdA[tid] = dA[(size_t)(t0 + tid) * NHEADS + head];
      sdt[tid] = dt[(size_t)(t0 + tid) * NHEADS + head];
    }
    __syncthreads();
    for (int t = 0; t < 64; ++t){
      float da = sdA[t];
      float sc = sdt[t] * sX[t][p];
      float yp = 0.f;
      #pragma unroll
      for (int j = 0; j < 16; ++j){
        float hv = fmaf(da, h[j], sc * sB[t][n0 + j]);
        h[j] = hv;
        yp = fmaf(hv, sC[t][n0 + j], yp);
      }
      yp += __shfl_down(yp, 2, 4);
      yp += __shfl_down(yp, 1, 4);
      if (nq == 0) y[(size_t)(t0 + t) * DINNER + head * HEADDIM + p] = yp + Dh * sX[t][p];
    }
  }
}

// yn = rms(y * silu(z)) * mnorm_w   (rows of 2048)
__global__ __launch_bounds__(256) void k_gate_rms(
    const float* __restrict__ y, const float* __restrict__ zx,
    const float* __restrict__ mw, float* __restrict__ yn)
{
  int row = blockIdx.x, tid = threadIdx.x;
  float v[8]; float ss = 0.f;
  #pragma unroll
  for (int i = 0; i < 8; ++i){
    int d = tid + i * 256;
    float z = zx[(size_t)row * DPROJ + d];
    float g = y[(size_t)row * DINNER + d] * siluf(z);
    v[i] = g; ss += g * g;
  }
  ss = block_reduce_sum_256(ss);
  float inv = rsqrtf(ss / (float)DINNER + 1e-6f);
  #pragma unroll
  for (int i = 0; i < 8; ++i){
    int d = tid + i * 256;
    yn[(size_t)row * DINNER + d] = v[i] * inv * mw[d];
  }
}

// x2 = xres + ssm_scale*yo ; hb = rms(x2)*ffn_norm_w
__global__ __launch_bounds__(256) void k_res_rms(
    const float* __restrict__ xres, const float* __restrict__ yo,
    const float* __restrict__ scale, const float* __restrict__ nw,
    float* __restrict__ x2, float* __restrict__ hb)
{
  int row = blockIdx.x, tid = threadIdx.x;
  float v[4]; float ss = 0.f;
  #pragma unroll
  for (int i = 0; i < 4; ++i){
    int d = tid + i * 256;
    float a = xres[(size_t)row * DMODEL + d] + scale[d] * yo[(size_t)row * DMODEL + d];
    v[i] = a; ss += a * a;
    x2[(size_t)row * DMODEL + d] = a;
  }
  ss = block_reduce_sum_256(ss);
  float inv = rsqrtf(ss / (float)DMODEL + 1e-6f);
  #pragma unroll
  for (int i = 0; i < 4; ++i){
    int d = tid + i * 256;
    hb[(size_t)row * DMODEL + d] = v[i] * inv * nw[d];
  }
}

__global__ __launch_bounds__(256) void k_swiglu(const float* __restrict__ gu, float* __restrict__ act)
{
  int idx = blockIdx.x * 256 + threadIdx.x;
  if (idx >= LSEQ * FFNHID) return;
  int l = idx / FFNHID, j = idx - l * FFNHID;
  float g  = gu[(size_t)l * (2*FFNHID) + j];
  float uu = gu[(size_t)l * (2*FFNHID) + FFNHID + j];
  act[idx] = siluf(g) * uu;
}

__global__ __launch_bounds__(256) void k_final(
    const float* __restrict__ x2, const float* __restrict__ dwn,
    const float* __restrict__ scale, float* __restrict__ out)
{
  int idx = blockIdx.x * 256 + threadIdx.x;
  if (idx >= LSEQ * DMODEL) return;
  int d = idx & (DMODEL - 1);
  out[idx] = x2[idx] + scale[d] * dwn[idx];
}

extern "C" void kernel_launch(void* const* d_in, const int* in_sizes, int n_in,
                              void* d_out, int out_size, void* d_ws, size_t ws_size,
                              hipStream_t stream)
{
  const float* x      = (const float*)d_in[0];
  const float* x0     = (const float*)d_in[1];
  // d_in[2] = mem (unused by reference)
  const float* rm     = (const float*)d_in[3];
  const float* sscale = (const float*)d_in[4];
  const float* mscale = (const float*)d_in[5];
  const float* snw    = (const float*)d_in[6];
  const float* fnw    = (const float*)d_in[7];
  const float* win    = (const float*)d_in[8];
  const float* cw     = (const float*)d_in[9];
  const float* cb     = (const float*)d_in[10];
  const float* dtb    = (const float*)d_in[11];
  const float* alog   = (const float*)d_in[12];
  const float* Dp     = (const float*)d_in[13];
  const float* mnw    = (const float*)d_in[14];
  const float* wout   = (const float*)d_in[15];
  const float* wgu    = (const float*)d_in[16];
  const float* wdn    = (const float*)d_in[17];
  float* out = (float*)d_out;

  // Workspace layout (MiB, manually reused; peak requirement = 116 MiB):
  //  [0,8)    xres            (alive until k_res_rms)
  //  [8,16)   u -> yo -> dwn  (sequentially reused)
  //  [16,64)  zx (33.25, dead after k_gate_rms) -> gu (48)
  //  [50,67)  xbc (17, dead after k_scan; overlaps gu region, which is written later)
  //  [67,68)  dt, dA
  //  [68,92)  y (16, dead after k_gate_rms) -> act (24)
  //  [84,100) yn (dead after GEMM2; overlaps act, written later)
  //  [100,108) x2
  //  [108,116) hb
  const size_t MB = 1024ull * 1024ull;
  char* ws = (char*)d_ws;
  float* xres  = (float*)(ws + 0*MB);
  float* u     = (float*)(ws + 8*MB);
  float* zx    = (float*)(ws + 16*MB);
  float* xbc   = (float*)(ws + 50*MB);
  float* dtbuf = (float*)(ws + 67*MB);
  float* dAbuf = (float*)(ws + 67*MB + 512*1024);
  float* yb    = (float*)(ws + 68*MB);
  float* yn    = (float*)(ws + 84*MB);
  float* x2    = (float*)(ws + 100*MB);
  float* hb    = (float*)(ws + 108*MB);
  float* gu    = (float*)(ws + 16*MB);
  float* act   = (float*)(ws + 68*MB);
  float* yo    = u;
  float* dwn   = u;

  dim3 blk(256);
  k_mix_rms<<<LSEQ, blk, 0, stream>>>(x, x0, rm, snw, xres, u);
  { dim3 g((DPROJ + 63)/64, LSEQ/64);
    k_gemm<<<g, blk, 0, stream>>>(u, win, zx, LSEQ, DPROJ, DMODEL); }
  k_conv<<<(LSEQ*CONVDIM + 255)/256, blk, 0, stream>>>(zx, cw, cb, xbc);
  k_dt<<<(LSEQ*NHEADS + 255)/256, blk, 0, stream>>>(zx, dtb, alog, dtbuf, dAbuf);
  k_scan<<<NHEADS, blk, 0, stream>>>(xbc, dtbuf, dAbuf, Dp, yb);
  k_gate_rms<<<LSEQ, blk, 0, stream>>>(yb, zx, mnw, yn);
  { dim3 g(DMODEL/64, LSEQ/64);
    k_gemm<<<g, blk, 0, stream>>>(yn, wout, yo, LSEQ, DMODEL, DINNER); }
  k_res_rms<<<LSEQ, blk, 0, stream>>>(xres, yo, sscale, fnw, x2, hb);
  { dim3 g((2*FFNHID)/64, LSEQ/64);
    k_gemm<<<g, blk, 0, stream>>>(hb, wgu, gu, LSEQ, 2*FFNHID, DMODEL); }
  k_swiglu<<<(LSEQ*FFNHID + 255)/256, blk, 0, stream>>>(gu, act);
  { dim3 g(DMODEL/64, LSEQ/64);
    k_gemm<<<g, blk, 0, stream>>>(act, wdn, dwn, LSEQ, DMODEL, FFNHID); }
  k_final<<<(LSEQ*DMODEL + 255)/256, blk, 0, stream>>>(x2, dwn, mscale, out);
}

// Round 2
// 445.964 us; speedup vs baseline: 3.6947x; 3.6947x over previous
//
#include <hip/hip_runtime.h>
#include <hip/hip_bf16.h>
#include <math.h>

#define LSEQ 2048
#define DMODEL 1024
#define DINNER 2048
#define NHEADS 32
#define HEADDIM 64
#define DSTATE 64
#define CONVDIM 2176     // DINNER + 2*DSTATE
#define XBCDT_W 2304     // padded width of (xBC | dt) block
#define FFNHID 3072

typedef float f32x4 __attribute__((ext_vector_type(4)));
typedef __bf16 bf16x8 __attribute__((ext_vector_type(8)));
typedef __hip_bfloat16 bf16;

__device__ __forceinline__ float siluf(float x){ return x / (1.0f + expf(-x)); }

__device__ __forceinline__ float block_reduce_sum_256(float v){
  #pragma unroll
  for (int o = 32; o > 0; o >>= 1) v += __shfl_down(v, o, 64);
  __shared__ float sh[4];
  int lane = threadIdx.x & 63;
  int w = threadIdx.x >> 6;
  if (lane == 0) sh[w] = v;
  __syncthreads();
  return sh[0] + sh[1] + sh[2] + sh[3];
}

// fp32 -> bf16 cast; tail [valid,total) zero-filled (row padding)
__global__ __launch_bounds__(256) void k_cast(
    const float* __restrict__ src, bf16* __restrict__ dst, int total, int valid)
{
  int idx = blockIdx.x * 256 + threadIdx.x;
  if (idx >= total) return;
  float v = (idx < valid) ? src[idx] : 0.f;
  dst[idx] = __float2bfloat16(v);
}

// x_res = rm0*x + rm1*x0 ; u = bf16(rms(x_res)*ssm_norm_w)
__global__ __launch_bounds__(256) void k_mix_rms(
    const float* __restrict__ x, const float* __restrict__ x0,
    const float* __restrict__ rm, const float* __restrict__ nw,
    float* __restrict__ xres, bf16* __restrict__ u)
{
  int row = blockIdx.x, tid = threadIdx.x;
  const float* xr  = x  + (size_t)row * DMODEL;
  const float* x0r = x0 + (size_t)row * DMODEL;
  float v[4]; float ss = 0.f;
  #pragma unroll
  for (int i = 0; i < 4; ++i){
    int d = tid + i * 256;
    float a = rm[d] * xr[d] + rm[DMODEL + d] * x0r[d];
    v[i] = a; ss += a * a;
    xres[(size_t)row * DMODEL + d] = a;
  }
  ss = block_reduce_sum_256(ss);
  float inv = rsqrtf(ss / (float)DMODEL + 1e-6f);
  #pragma unroll
  for (int i = 0; i < 4; ++i){
    int d = tid + i * 256;
    u[(size_t)row * DMODEL + d] = __float2bfloat16(v[i] * inv * nw[d]);
  }
}

// ---------------- bf16 MFMA GEMM: C[M=2048][N] = A[M][K] @ W[N][K]^T ----------------
// 128x128 tile, BK=32, 4 waves (2x2), each wave 64x64 = 4x4 fragments of 16x16x32.
// LDS row stride 56 elems (112B): 16B-aligned b128 reads, 2-way-conflict only.
#define LDSW 56

__global__ __launch_bounds__(256) void k_gemm_bf16(
    const bf16* __restrict__ A, const bf16* __restrict__ W,
    float* __restrict__ C, int K, int N)
{
  __shared__ __align__(16) bf16 As[128 * LDSW];
  __shared__ __align__(16) bf16 Ws[128 * LDSW];
  int tid = threadIdx.x;
  int bm = blockIdx.y * 128, bn = blockIdx.x * 128;
  int lane = tid & 63, wid = tid >> 6;
  int wm = (wid >> 1) * 64, wn = (wid & 1) * 64;
  int r16 = lane & 15, g8 = lane >> 4;
  int sm = tid >> 2, sc = (tid & 3) * 8;
  f32x4 acc[4][4];
  #pragma unroll
  for (int i = 0; i < 4; ++i)
    #pragma unroll
    for (int j = 0; j < 4; ++j) acc[i][j] = (f32x4){0.f,0.f,0.f,0.f};

  for (int k0 = 0; k0 < K; k0 += 32){
    uint4 a0 = *(const uint4*)(A + (size_t)(bm + sm)      * K + k0 + sc);
    uint4 a1 = *(const uint4*)(A + (size_t)(bm + 64 + sm) * K + k0 + sc);
    uint4 w0 = *(const uint4*)(W + (size_t)(bn + sm)      * K + k0 + sc);
    uint4 w1 = *(const uint4*)(W + (size_t)(bn + 64 + sm) * K + k0 + sc);
    __syncthreads();
    *(uint4*)(As + sm * LDSW + sc) = a0;
    *(uint4*)(As + (64 + sm) * LDSW + sc) = a1;
    *(uint4*)(Ws + sm * LDSW + sc) = w0;
    *(uint4*)(Ws + (64 + sm) * LDSW + sc) = w1;
    __syncthreads();
    bf16x8 af[4], bf[4];
    #pragma unroll
    for (int i = 0; i < 4; ++i)
      af[i] = *(const bf16x8*)(As + (wm + i*16 + r16) * LDSW + g8 * 8);
    #pragma unroll
    for (int j = 0; j < 4; ++j)
      bf[j] = *(const bf16x8*)(Ws + (wn + j*16 + r16) * LDSW + g8 * 8);
    #pragma unroll
    for (int i = 0; i < 4; ++i)
      #pragma unroll
      for (int j = 0; j < 4; ++j)
        acc[i][j] = __builtin_amdgcn_mfma_f32_16x16x32_bf16(af[i], bf[j], acc[i][j], 0, 0, 0);
  }
  #pragma unroll
  for (int i = 0; i < 4; ++i){
    int row = bm + wm + i*16 + g8*4;
    #pragma unroll
    for (int j = 0; j < 4; ++j){
      int col = bn + wn + j*16 + r16;
      #pragma unroll
      for (int r = 0; r < 4; ++r)
        C[(size_t)(row + r) * N + col] = acc[i][j][r];
    }
  }
}

// FFN gate_up GEMM with fused SwiGLU: act = bf16(silu(A@Wg^T) * (A@Wu^T))
__global__ __launch_bounds__(256) void k_gemm_ffn(
    const bf16* __restrict__ A, const bf16* __restrict__ Wg, const bf16* __restrict__ Wu,
    bf16* __restrict__ act, int K)
{
  __shared__ __align__(16) bf16 As[128 * LDSW];
  __shared__ __align__(16) bf16 Gs[128 * LDSW];
  __shared__ __align__(16) bf16 Us[128 * LDSW];
  int tid = threadIdx.x;
  int bm = blockIdx.y * 128, bn = blockIdx.x * 128;
  int lane = tid & 63, wid = tid >> 6;
  int wm = (wid >> 1) * 64, wn = (wid & 1) * 64;
  int r16 = lane & 15, g8 = lane >> 4;
  int sm = tid >> 2, sc = (tid & 3) * 8;
  f32x4 accg[4][4], accu[4][4];
  #pragma unroll
  for (int i = 0; i < 4; ++i)
    #pragma unroll
    for (int j = 0; j < 4; ++j){
      accg[i][j] = (f32x4){0.f,0.f,0.f,0.f};
      accu[i][j] = (f32x4){0.f,0.f,0.f,0.f};
    }
  for (int k0 = 0; k0 < K; k0 += 32){
    uint4 a0 = *(const uint4*)(A  + (size_t)(bm + sm)      * K + k0 + sc);
    uint4 a1 = *(const uint4*)(A  + (size_t)(bm + 64 + sm) * K + k0 + sc);
    uint4 g0 = *(const uint4*)(Wg + (size_t)(bn + sm)      * K + k0 + sc);
    uint4 g1 = *(const uint4*)(Wg + (size_t)(bn + 64 + sm) * K + k0 + sc);
    uint4 u0 = *(const uint4*)(Wu + (size_t)(bn + sm)      * K + k0 + sc);
    uint4 u1 = *(const uint4*)(Wu + (size_t)(bn + 64 + sm) * K + k0 + sc);
    __syncthreads();
    *(uint4*)(As + sm * LDSW + sc) = a0;
    *(uint4*)(As + (64 + sm) * LDSW + sc) = a1;
    *(uint4*)(Gs + sm * LDSW + sc) = g0;
    *(uint4*)(Gs + (64 + sm) * LDSW + sc) = g1;
    *(uint4*)(Us + sm * LDSW + sc) = u0;
    *(uint4*)(Us + (64 + sm) * LDSW + sc) = u1;
    __syncthreads();
    bf16x8 af[4], gf[4], uf[4];
    #pragma unroll
    for (int i = 0; i < 4; ++i)
      af[i] = *(const bf16x8*)(As + (wm + i*16 + r16) * LDSW + g8 * 8);
    #pragma unroll
    for (int j = 0; j < 4; ++j){
      gf[j] = *(const bf16x8*)(Gs + (wn + j*16 + r16) * LDSW + g8 * 8);
      uf[j] = *(const bf16x8*)(Us + (wn + j*16 + r16) * LDSW + g8 * 8);
    }
    #pragma unroll
    for (int i = 0; i < 4; ++i)
      #pragma unroll
      for (int j = 0; j < 4; ++j){
        accg[i][j] = __builtin_amdgcn_mfma_f32_16x16x32_bf16(af[i], gf[j], accg[i][j], 0, 0, 0);
        accu[i][j] = __builtin_amdgcn_mfma_f32_16x16x32_bf16(af[i], uf[j], accu[i][j], 0, 0, 0);
      }
  }
  #pragma unroll
  for (int i = 0; i < 4; ++i){
    int row = bm + wm + i*16 + g8*4;
    #pragma unroll
    for (int j = 0; j < 4; ++j){
      int col = bn + wn + j*16 + r16;
      #pragma unroll
      for (int r = 0; r < 4; ++r){
        float g = accg[i][j][r], u = accu[i][j][r];
        act[(size_t)(row + r) * FFNHID + col] = __float2bfloat16(siluf(g) * u);
      }
    }
  }
}

// down GEMM with fused final residual: out = x2 + mscale * (A @ W^T)
__global__ __launch_bounds__(256) void k_gemm_down(
    const bf16* __restrict__ A, const bf16* __restrict__ W,
    const float* __restrict__ x2, const float* __restrict__ mscale,
    float* __restrict__ out, int K)
{
  __shared__ __align__(16) bf16 As[128 * LDSW];
  __shared__ __align__(16) bf16 Ws[128 * LDSW];
  int tid = threadIdx.x;
  int bm = blockIdx.y * 128, bn = blockIdx.x * 128;
  int lane = tid & 63, wid = tid >> 6;
  int wm = (wid >> 1) * 64, wn = (wid & 1) * 64;
  int r16 = lane & 15, g8 = lane >> 4;
  int sm = tid >> 2, sc = (tid & 3) * 8;
  f32x4 acc[4][4];
  #pragma unroll
  for (int i = 0; i < 4; ++i)
    #pragma unroll
    for (int j = 0; j < 4; ++j) acc[i][j] = (f32x4){0.f,0.f,0.f,0.f};
  for (int k0 = 0; k0 < K; k0 += 32){
    uint4 a0 = *(const uint4*)(A + (size_t)(bm + sm)      * K + k0 + sc);
    uint4 a1 = *(const uint4*)(A + (size_t)(bm + 64 + sm) * K + k0 + sc);
    uint4 w0 = *(const uint4*)(W + (size_t)(bn + sm)      * K + k0 + sc);
    uint4 w1 = *(const uint4*)(W + (size_t)(bn + 64 + sm) * K + k0 + sc);
    __syncthreads();
    *(uint4*)(As + sm * LDSW + sc) = a0;
    *(uint4*)(As + (64 + sm) * LDSW + sc) = a1;
    *(uint4*)(Ws + sm * LDSW + sc) = w0;
    *(uint4*)(Ws + (64 + sm) * LDSW + sc) = w1;
    __syncthreads();
    bf16x8 af[4], bf[4];
    #pragma unroll
    for (int i = 0; i < 4; ++i)
      af[i] = *(const bf16x8*)(As + (wm + i*16 + r16) * LDSW + g8 * 8);
    #pragma unroll
    for (int j = 0; j < 4; ++j)
      bf[j] = *(const bf16x8*)(Ws + (wn + j*16 + r16) * LDSW + g8 * 8);
    #pragma unroll
    for (int i = 0; i < 4; ++i)
      #pragma unroll
      for (int j = 0; j < 4; ++j)
        acc[i][j] = __builtin_amdgcn_mfma_f32_16x16x32_bf16(af[i], bf[j], acc[i][j], 0, 0, 0);
  }
  #pragma unroll
  for (int i = 0; i < 4; ++i){
    int row = bm + wm + i*16 + g8*4;
    #pragma unroll
    for (int j = 0; j < 4; ++j){
      int col = bn + wn + j*16 + r16;
      #pragma unroll
      for (int r = 0; r < 4; ++r){
        size_t o = (size_t)(row + r) * DMODEL + col;
        out[o] = x2[o] + mscale[col] * acc[i][j][r];
      }
    }
  }
}

// causal depthwise conv4 + bias + silu over xbcdt cols [0,CONVDIM)
__global__ __launch_bounds__(256) void k_conv(
    const float* __restrict__ xbcdt, const float* __restrict__ cw,
    const float* __restrict__ cb, float* __restrict__ xbc)
{
  int idx = blockIdx.x * 256 + threadIdx.x;
  if (idx >= LSEQ * CONVDIM) return;
  int l = idx / CONVDIM, c = idx - l * CONVDIM;
  float acc = cb[c];
  #pragma unroll
  for (int k = 0; k < 4; ++k){
    int t = l + k - 3;
    if (t >= 0) acc = fmaf(xbcdt[(size_t)t * XBCDT_W + c], cw[c*4 + k], acc);
  }
  xbc[idx] = siluf(acc);
}

// dt = softplus(raw + dt_bias); la = -exp(A_log)*dt  (log of decay)
__global__ __launch_bounds__(256) void k_dt(
    const float* __restrict__ xbcdt, const float* __restrict__ dtb,
    const float* __restrict__ alog, float* __restrict__ dtv, float* __restrict__ lav)
{
  int idx = blockIdx.x * 256 + threadIdx.x;
  if (idx >= LSEQ * NHEADS) return;
  int h = idx & (NHEADS - 1);
  int l = idx >> 5;
  float raw = xbcdt[(size_t)l * XBCDT_W + CONVDIM + h] + dtb[h];
  float d = (raw > 20.f) ? raw : log1pf(expf(raw));
  dtv[idx] = d;
  lav[idx] = -expf(alog[h]) * d;
}

// chunked SSD pass A: per (head,chunk) T[p][n] = sum_j prod_{r>j}(a_r)*dt_j*x[j,p]*B[j,n]
__global__ __launch_bounds__(256) void k_scanA(
    const float* __restrict__ xbc, const float* __restrict__ dtv,
    const float* __restrict__ lav, float* __restrict__ T, float* __restrict__ ctot)
{
  __shared__ float sB[4096];
  __shared__ float sx[4096];
  __shared__ float sla[64], sdt[64], sa[64];
  int h = blockIdx.x >> 5, c = blockIdx.x & 31;
  int tid = threadIdx.x, t0 = c * 64;
  if (tid < 64){
    sla[tid] = lav[(size_t)(t0 + tid) * NHEADS + h];
    sdt[tid] = dtv[(size_t)(t0 + tid) * NHEADS + h];
  }
  for (int idx = tid; idx < 4096; idx += 256){
    int j = idx >> 6, n = idx & 63;
    size_t rb = (size_t)(t0 + j) * CONVDIM;
    sB[idx] = xbc[rb + DINNER + n];
    sx[idx] = xbc[rb + h * HEADDIM + n];
  }
  __syncthreads();
  if (tid < 64) sa[tid] = expf(sla[tid]);
  __syncthreads();
  int p = tid >> 2, n0 = (tid & 3) << 4;
  float acc[16];
  #pragma unroll
  for (int nn = 0; nn < 16; ++nn) acc[nn] = 0.f;
  float w = 1.f;
  for (int j = 63; j >= 0; --j){
    float cw = w * sdt[j] * sx[j*64 + p];
    #pragma unroll
    for (int nn = 0; nn < 16; ++nn) acc[nn] = fmaf(cw, sB[j*64 + n0 + nn], acc[nn]);
    w *= sa[j];
  }
  size_t ob = (size_t)blockIdx.x * 4096 + (size_t)p * 64 + n0;
  #pragma unroll
  for (int nn = 0; nn < 16; ++nn) T[ob + nn] = acc[nn];
  if (tid == 0) ctot[blockIdx.x] = w;
}

// pass B: sequential state recurrence over chunks; stores S_in in place of T
__global__ __launch_bounds__(256) void k_scanB(float* __restrict__ T, const float* __restrict__ ctot)
{
  int h = blockIdx.x >> 3, e = blockIdx.x & 7;
  int tid = threadIdx.x;
  size_t off = (size_t)e * 512 + tid * 2;
  float s0 = 0.f, s1 = 0.f;
  for (int c = 0; c < 32; ++c){
    float ct = ctot[h * 32 + c];
    size_t base = (size_t)(h * 32 + c) * 4096 + off;
    float2 tv = *(const float2*)&T[base];
    *(float2*)&T[base] = make_float2(s0, s1);
    s0 = fmaf(ct, s0, tv.x);
    s1 = fmaf(ct, s1, tv.y);
  }
}

// pass C: y[i,p] = intra(masked CB^T @ dt*x) + prod_a * (C @ S_in^T) + D*x
__global__ __launch_bounds__(256) void k_scanC(
    const float* __restrict__ xbc, const float* __restrict__ Sin,
    const float* __restrict__ dtv, const float* __restrict__ lav,
    const float* __restrict__ Dp, float* __restrict__ y)
{
  __shared__ float sC[4096];
  __shared__ float sBG[4096];   // B, then overwritten with G = C@B^T
  __shared__ float sS[4096];
  __shared__ bf16 sx[4096];
  __shared__ float sla[64], sdt[64], sa[64];
  int h = blockIdx.x >> 5, c = blockIdx.x & 31;
  int tid = threadIdx.x, t0 = c * 64;
  if (tid < 64){
    sla[tid] = lav[(size_t)(t0 + tid) * NHEADS + h];
    sdt[tid] = dtv[(size_t)(t0 + tid) * NHEADS + h];
  }
  for (int idx = tid; idx < 4096; idx += 256){
    int j = idx >> 6, n = idx & 63;
    size_t rb = (size_t)(t0 + j) * CONVDIM;
    sBG[idx] = xbc[rb + DINNER + n];
    sC[idx]  = xbc[rb + DINNER + DSTATE + n];
    sx[idx]  = __float2bfloat16(xbc[rb + h * HEADDIM + n]);
    sS[idx]  = Sin[(size_t)blockIdx.x * 4096 + idx];
  }
  __syncthreads();
  if (tid < 64) sa[tid] = expf(sla[tid]);
  __syncthreads();
  int i = tid >> 2, q0 = (tid & 3) << 4;   // q0 = j-group for G, p-group for y
  // G[i][j] = sum_n C[i,n] B[j,n]
  float g[16];
  #pragma unroll
  for (int jj = 0; jj < 16; ++jj) g[jj] = 0.f;
  for (int n = 0; n < 64; ++n){
    float cin = sC[i*64 + n];
    #pragma unroll
    for (int jj = 0; jj < 16; ++jj) g[jj] = fmaf(cin, sBG[(q0 + jj)*64 + n], g[jj]);
  }
  __syncthreads();
  #pragma unroll
  for (int jj = 0; jj < 16; ++jj) sBG[i*64 + q0 + jj] = g[jj];
  __syncthreads();
  // intra-chunk (descending j with running decay product)
  float accI[16];
  #pragma unroll
  for (int pp = 0; pp < 16; ++pp) accI[pp] = 0.f;
  float w = 1.f;
  for (int j = i; j >= 0; --j){
    float coef = w * sBG[i*64 + j] * sdt[j];
    #pragma unroll
    for (int pp = 0; pp < 16; ++pp)
      accI[pp] = fmaf(coef, __bfloat162float(sx[j*64 + q0 + pp]), accI[pp]);
    w *= sa[j];
  }
  // inter-chunk: w now = prod_{r<=i} a_r
  float accS[16];
  #pragma unroll
  for (int pp = 0; pp < 16; ++pp) accS[pp] = 0.f;
  for (int n = 0; n < 64; ++n){
    float cin = sC[i*64 + n];
    #pragma unroll
    for (int pp = 0; pp < 16; ++pp)
      accS[pp] = fmaf(cin, sS[(q0 + pp)*64 + n], accS[pp]);
  }
  float Dh = Dp[h];
  size_t yb = (size_t)(t0 + i) * DINNER + h * HEADDIM + q0;
  #pragma unroll
  for (int pp = 0; pp < 16; ++pp)
    y[yb + pp] = accI[pp] + w * accS[pp] + Dh * __bfloat162float(sx[i*64 + q0 + pp]);
}

// yn = bf16(rms(y * silu(z)) * mnorm_w)
__global__ __launch_bounds__(256) void k_gate_rms(
    const float* __restrict__ y, const float* __restrict__ zbuf,
    const float* __restrict__ mw, bf16* __restrict__ yn)
{
  int row = blockIdx.x, tid = threadIdx.x;
  float v[8]; float ss = 0.f;
  #pragma unroll
  for (int i = 0; i < 8; ++i){
    int d = tid + i * 256;
    float z = zbuf[(size_t)row * DINNER + d];
    float g = y[(size_t)row * DINNER + d] * siluf(z);
    v[i] = g; ss += g * g;
  }
  ss = block_reduce_sum_256(ss);
  float inv = rsqrtf(ss / (float)DINNER + 1e-6f);
  #pragma unroll
  for (int i = 0; i < 8; ++i){
    int d = tid + i * 256;
    yn[(size_t)row * DINNER + d] = __float2bfloat16(v[i] * inv * mw[d]);
  }
}

// x2 = xres + ssm_scale*yo ; hb = bf16(rms(x2)*ffn_norm_w)
__global__ __launch_bounds__(256) void k_res_rms(
    const float* __restrict__ xres, const float* __restrict__ yo,
    const float* __restrict__ scale, const float* __restrict__ nw,
    float* __restrict__ x2, bf16* __restrict__ hb)
{
  int row = blockIdx.x, tid = threadIdx.x;
  float v[4]; float ss = 0.f;
  #pragma unroll
  for (int i = 0; i < 4; ++i){
    int d = tid + i * 256;
    float a = xres[(size_t)row * DMODEL + d] + scale[d] * yo[(size_t)row * DMODEL + d];
    v[i] = a; ss += a * a;
    x2[(size_t)row * DMODEL + d] = a;
  }
  ss = block_reduce_sum_256(ss);
  float inv = rsqrtf(ss / (float)DMODEL + 1e-6f);
  #pragma unroll
  for (int i = 0; i < 4; ++i){
    int d = tid + i * 256;
    hb[(size_t)row * DMODEL + d] = __float2bfloat16(v[i] * inv * nw[d]);
  }
}

extern "C" void kernel_launch(void* const* d_in, const int* in_sizes, int n_in,
                              void* d_out, int out_size, void* d_ws, size_t ws_size,
                              hipStream_t stream)
{
  const float* x      = (const float*)d_in[0];
  const float* x0     = (const float*)d_in[1];
  const float* rm     = (const float*)d_in[3];
  const float* sscale = (const float*)d_in[4];
  const float* mscale = (const float*)d_in[5];
  const float* snw    = (const float*)d_in[6];
  const float* fnw    = (const float*)d_in[7];
  const float* win    = (const float*)d_in[8];
  const float* cw     = (const float*)d_in[9];
  const float* cb     = (const float*)d_in[10];
  const float* dtb    = (const float*)d_in[11];
  const float* alog   = (const float*)d_in[12];
  const float* Dp     = (const float*)d_in[13];
  const float* mnw    = (const float*)d_in[14];
  const float* wout   = (const float*)d_in[15];
  const float* wgu    = (const float*)d_in[16];
  const float* wdn    = (const float*)d_in[17];
  float* out = (float*)d_out;

  // Workspace layout (byte offsets in MiB), lifetime-overlapped; peak 114 MiB:
  //  [0,13)    winb (8.5, dead after in_proj GEMMs) -> act bf16 (12)
  //  [13,17)   woutb
  //  [17,29)   wgub
  //  [29,35)   wdnb
  //  [35,43)   xres
  //  [43,47)   u bf16 (dead after in_proj) -> dt+la (dead after scanC) -> hb bf16
  //  [47,63)   zbuf (dead after gate_rms); x2 at [47,55) written later
  //  [63,81)   xbcdt (dead after k_dt) -> y (16) at [63,79)
  //  [81,98)   xbc (dead after scanC) -> yo at [81,89)
  //  [98,114)  T/Sin (dead after scanC) -> yn bf16 at [98,106)
  //  [114,..)  ctot (4KB)
  const size_t MB = 1024ull * 1024ull;
  char* ws = (char*)d_ws;
  bf16*  winb  = (bf16*) (ws + 0*MB);
  bf16*  act   = (bf16*) (ws + 0*MB);
  bf16*  woutb = (bf16*) (ws + 13*MB);
  bf16*  wgub  = (bf16*) (ws + 17*MB);
  bf16*  wdnb  = (bf16*) (ws + 29*MB);
  float* xres  = (float*)(ws + 35*MB);
  bf16*  u     = (bf16*) (ws + 43*MB);
  float* dtv   = (float*)(ws + 43*MB);
  float* lav   = (float*)(ws + 43*MB + 256*1024);
  bf16*  hb    = (bf16*) (ws + 43*MB);
  float* zbuf  = (float*)(ws + 47*MB);
  float* x2    = (float*)(ws + 47*MB);
  float* xbcdt = (float*)(ws + 63*MB);
  float* yb    = (float*)(ws + 63*MB);
  float* xbc   = (float*)(ws + 81*MB);
  float* yo    = (float*)(ws + 81*MB);
  float* T     = (float*)(ws + 98*MB);
  bf16*  yn    = (bf16*) (ws + 98*MB);
  float* ctot  = (float*)(ws + 114*MB);

  dim3 blk(256);
  // weight casts (bf16; winb padded 4256->4352 rows)
  k_cast<<<(4352*1024+255)/256, blk, 0, stream>>>(win,  winb,  4352*1024, 4256*1024);
  k_cast<<<(1024*2048+255)/256, blk, 0, stream>>>(wout, woutb, 1024*2048, 1024*2048);
  k_cast<<<(6144*1024+255)/256, blk, 0, stream>>>(wgu,  wgub,  6144*1024, 6144*1024);
  k_cast<<<(1024*3072+255)/256, blk, 0, stream>>>(wdn,  wdnb,  1024*3072, 1024*3072);

  k_mix_rms<<<LSEQ, blk, 0, stream>>>(x, x0, rm, snw, xres, u);
  // in_proj split: z cols [0,2048) -> zbuf ; cols [2048,4352) -> xbcdt
  k_gemm_bf16<<<dim3(16,16), blk, 0, stream>>>(u, winb,            zbuf,  DMODEL, DINNER);
  k_gemm_bf16<<<dim3(18,16), blk, 0, stream>>>(u, winb + (size_t)2048*1024, xbcdt, DMODEL, XBCDT_W);
  k_conv<<<(LSEQ*CONVDIM+255)/256, blk, 0, stream>>>(xbcdt, cw, cb, xbc);
  k_dt<<<(LSEQ*NHEADS)/256, blk, 0, stream>>>(xbcdt, dtb, alog, dtv, lav);
  k_scanA<<<NHEADS*32, blk, 0, stream>>>(xbc, dtv, lav, T, ctot);
  k_scanB<<<NHEADS*8, blk, 0, stream>>>(T, ctot);
  k_scanC<<<NHEADS*32, blk, 0, stream>>>(xbc, T, dtv, lav, Dp, yb);
  k_gate_rms<<<LSEQ, blk, 0, stream>>>(yb, zbuf, mnw, yn);
  k_gemm_bf16<<<dim3(8,16), blk, 0, stream>>>(yn, woutb, yo, DINNER, DMODEL);
  k_res_rms<<<LSEQ, blk, 0, stream>>>(xres, yo, sscale, fnw, x2, hb);
  k_gemm_ffn<<<dim3(24,16), blk, 0, stream>>>(hb, wgub, wgub + (size_t)3072*1024, act, DMODEL);
  k_gemm_down<<<dim3(8,16), blk, 0, stream>>>(act, wdnb, x2, mscale, out, FFNHID);
}

// Round 3
// 412.911 us; speedup vs baseline: 3.9905x; 1.0800x over previous
//
#include <hip/hip_runtime.h>
#include <hip/hip_bf16.h>
#include <math.h>

#define LSEQ 2048
#define DMODEL 1024
#define DINNER 2048
#define NHEADS 32
#define HEADDIM 64
#define DSTATE 64
#define CONVDIM 2176     // DINNER + 2*DSTATE
#define XBCDT_W 2304     // padded width of (xBC | dt) block
#define FFNHID 3072

typedef float f32x4 __attribute__((ext_vector_type(4)));
typedef __bf16 bf16x8 __attribute__((ext_vector_type(8)));
typedef __hip_bfloat16 bf16;

__device__ __forceinline__ float siluf(float x){ return x / (1.0f + expf(-x)); }

// direct global->LDS DMA, 16B per lane; LDS dest is wave-uniform base + lane*16
#define GLOAD_LDS16(gp, lp) __builtin_amdgcn_global_load_lds( \
    (const __attribute__((address_space(1))) void*)(gp), \
    (__attribute__((address_space(3))) void*)(lp), 16, 0, 0)

__device__ __forceinline__ float block_reduce_sum_256(float v){
  #pragma unroll
  for (int o = 32; o > 0; o >>= 1) v += __shfl_down(v, o, 64);
  __shared__ float sh[4];
  int lane = threadIdx.x & 63;
  int w = threadIdx.x >> 6;
  if (lane == 0) sh[w] = v;
  __syncthreads();
  return sh[0] + sh[1] + sh[2] + sh[3];
}

__device__ __forceinline__ ushort bf16bits(float f){
  __hip_bfloat16 h = __float2bfloat16(f);
  return *reinterpret_cast<ushort*>(&h);
}

// all 4 weight casts in one dispatch, float4 -> 4x bf16 per thread
// segment boundaries in float4 units
__global__ __launch_bounds__(256) void k_cast_all(
    const float* __restrict__ w0, const float* __restrict__ w1,
    const float* __restrict__ w2, const float* __restrict__ w3,
    bf16* __restrict__ d0, bf16* __restrict__ d1,
    bf16* __restrict__ d2, bf16* __restrict__ d3)
{
  int idx = blockIdx.x * 256 + threadIdx.x;   // float4 index, total 3997696
  const float* s; bf16* d; int valid;
  if (idx < 1114112)              { s = w0; d = d0; valid = 1089536; }           // winb pad->4352 rows
  else if (idx < 1638400)         { idx -= 1114112; s = w1; d = d1; valid = 524288; }
  else if (idx < 3211264)         { idx -= 1638400; s = w2; d = d2; valid = 1572864; }
  else                            { idx -= 3211264; s = w3; d = d3; valid = 786432; }
  float4 v = (idx < valid) ? *(const float4*)(s + (size_t)idx * 4)
                           : make_float4(0.f, 0.f, 0.f, 0.f);
  ushort4 r;
  r.x = bf16bits(v.x); r.y = bf16bits(v.y); r.z = bf16bits(v.z); r.w = bf16bits(v.w);
  *(ushort4*)(d + (size_t)idx * 4) = r;
}

// x_res = rm0*x + rm1*x0 ; u = bf16(rms(x_res)*ssm_norm_w)
__global__ __launch_bounds__(256) void k_mix_rms(
    const float* __restrict__ x, const float* __restrict__ x0,
    const float* __restrict__ rm, const float* __restrict__ nw,
    float* __restrict__ xres, bf16* __restrict__ u)
{
  int row = blockIdx.x, tid = threadIdx.x;
  const float4* xr  = (const float4*)(x  + (size_t)row * DMODEL);
  const float4* x0r = (const float4*)(x0 + (size_t)row * DMODEL);
  float4 xv = xr[tid], x0v = x0r[tid];
  float4 r0 = ((const float4*)rm)[tid];
  float4 r1 = ((const float4*)(rm + DMODEL))[tid];
  float4 a;
  a.x = r0.x*xv.x + r1.x*x0v.x; a.y = r0.y*xv.y + r1.y*x0v.y;
  a.z = r0.z*xv.z + r1.z*x0v.z; a.w = r0.w*xv.w + r1.w*x0v.w;
  ((float4*)(xres + (size_t)row * DMODEL))[tid] = a;
  float ss = a.x*a.x + a.y*a.y + a.z*a.z + a.w*a.w;
  ss = block_reduce_sum_256(ss);
  float inv = rsqrtf(ss / (float)DMODEL + 1e-6f);
  float4 nv = ((const float4*)nw)[tid];
  ushort4 o;
  o.x = bf16bits(a.x*inv*nv.x); o.y = bf16bits(a.y*inv*nv.y);
  o.z = bf16bits(a.z*inv*nv.z); o.w = bf16bits(a.w*inv*nv.w);
  *(ushort4*)(u + (size_t)row * DMODEL + tid*4) = o;
}

// ---------- m97-style bf16 MFMA GEMM mainloop ----------
// 128x128 tile, BK=32, 4 waves (2x2), wave = 64x64 = 4x4 frags of 16x16x32.
// LDS linear [128][32] bf16 per matrix; staged via global_load_lds width 16.
// A,W must point at the tile origin rows (row stride K).
__device__ __forceinline__ void gemm_mainloop(
    const bf16* __restrict__ A, const bf16* __restrict__ W,
    int K, bf16* As, bf16* Ws, f32x4 acc[4][4])
{
  int tid = threadIdx.x;
  int lane = tid & 63, wid = tid >> 6;
  int wm = (wid >> 1) * 64, wn = (wid & 1) * 64;
  int r16 = lane & 15, g8 = lane >> 4;
  int srow = lane >> 2, scol = (lane & 3) * 8;
  const bf16* ga0 = A + (size_t)(wid*32 + srow) * K + scol;
  const bf16* ga1 = ga0 + (size_t)16 * K;
  const bf16* gw0 = W + (size_t)(wid*32 + srow) * K + scol;
  const bf16* gw1 = gw0 + (size_t)16 * K;
  bf16* lA0 = As + wid*1024; bf16* lA1 = lA0 + 512;
  bf16* lW0 = Ws + wid*1024; bf16* lW1 = lW0 + 512;
  for (int k0 = 0; k0 < K; k0 += 32){
    __syncthreads();
    GLOAD_LDS16(ga0 + k0, lA0);
    GLOAD_LDS16(ga1 + k0, lA1);
    GLOAD_LDS16(gw0 + k0, lW0);
    GLOAD_LDS16(gw1 + k0, lW1);
    __syncthreads();
    bf16x8 af[4], bfr[4];
    #pragma unroll
    for (int i = 0; i < 4; ++i)
      af[i] = *(const bf16x8*)(As + (wm + i*16 + r16)*32 + g8*8);
    #pragma unroll
    for (int j = 0; j < 4; ++j)
      bfr[j] = *(const bf16x8*)(Ws + (wn + j*16 + r16)*32 + g8*8);
    #pragma unroll
    for (int i = 0; i < 4; ++i)
      #pragma unroll
      for (int j = 0; j < 4; ++j)
        acc[i][j] = __builtin_amdgcn_mfma_f32_16x16x32_bf16(af[i], bfr[j], acc[i][j], 0, 0, 0);
  }
}

// in_proj: one dispatch, block cols [0,16) -> zbuf (N=2048), [16,34) -> xbcdt (N=2304)
__global__ __launch_bounds__(256) void k_gemm_inproj(
    const bf16* __restrict__ A, const bf16* __restrict__ Wfull,
    float* __restrict__ zbuf, float* __restrict__ xbcdt)
{
  __shared__ __align__(16) bf16 As[128*32];
  __shared__ __align__(16) bf16 Ws[128*32];
  int bx = blockIdx.x, by = blockIdx.y;
  f32x4 acc[4][4];
  #pragma unroll
  for (int i = 0; i < 4; ++i)
    #pragma unroll
    for (int j = 0; j < 4; ++j) acc[i][j] = (f32x4){0.f,0.f,0.f,0.f};
  gemm_mainloop(A + (size_t)(by*128)*DMODEL, Wfull + (size_t)(bx*128)*DMODEL,
                DMODEL, As, Ws, acc);
  int tid = threadIdx.x, lane = tid & 63, wid = tid >> 6;
  int wm = (wid >> 1) * 64, wn = (wid & 1) * 64;
  int r16 = lane & 15, g8 = lane >> 4;
  float* Cp; int ldc, col0;
  if (bx < 16){ Cp = zbuf;  ldc = DINNER;  col0 = bx*128; }
  else        { Cp = xbcdt; ldc = XBCDT_W; col0 = (bx-16)*128; }
  #pragma unroll
  for (int i = 0; i < 4; ++i){
    int row = by*128 + wm + i*16 + g8*4;
    #pragma unroll
    for (int j = 0; j < 4; ++j){
      int col = col0 + wn + j*16 + r16;
      #pragma unroll
      for (int r = 0; r < 4; ++r)
        Cp[(size_t)(row + r) * ldc + col] = acc[i][j][r];
    }
  }
}

// generic: C = A@W^T, fp32 out
__global__ __launch_bounds__(256) void k_gemm_plain(
    const bf16* __restrict__ A, const bf16* __restrict__ W,
    float* __restrict__ C, int K, int N)
{
  __shared__ __align__(16) bf16 As[128*32];
  __shared__ __align__(16) bf16 Ws[128*32];
  f32x4 acc[4][4];
  #pragma unroll
  for (int i = 0; i < 4; ++i)
    #pragma unroll
    for (int j = 0; j < 4; ++j) acc[i][j] = (f32x4){0.f,0.f,0.f,0.f};
  gemm_mainloop(A + (size_t)(blockIdx.y*128)*K, W + (size_t)(blockIdx.x*128)*K,
                K, As, Ws, acc);
  int tid = threadIdx.x, lane = tid & 63, wid = tid >> 6;
  int wm = (wid >> 1) * 64, wn = (wid & 1) * 64;
  int r16 = lane & 15, g8 = lane >> 4;
  #pragma unroll
  for (int i = 0; i < 4; ++i){
    int row = blockIdx.y*128 + wm + i*16 + g8*4;
    #pragma unroll
    for (int j = 0; j < 4; ++j){
      int col = blockIdx.x*128 + wn + j*16 + r16;
      #pragma unroll
      for (int r = 0; r < 4; ++r)
        C[(size_t)(row + r) * N + col] = acc[i][j][r];
    }
  }
}

// FFN gate_up with fused SwiGLU epilogue: act = bf16(silu(A@Wg^T) * (A@Wu^T))
__global__ __launch_bounds__(256) void k_gemm_ffn(
    const bf16* __restrict__ A, const bf16* __restrict__ Wg, const bf16* __restrict__ Wu,
    bf16* __restrict__ act, int K)
{
  __shared__ __align__(16) bf16 As[128*32];
  __shared__ __align__(16) bf16 Gs[128*32];
  __shared__ __align__(16) bf16 Us[128*32];
  int tid = threadIdx.x;
  int lane = tid & 63, wid = tid >> 6;
  int wm = (wid >> 1) * 64, wn = (wid & 1) * 64;
  int r16 = lane & 15, g8 = lane >> 4;
  int srow = lane >> 2, scol = (lane & 3) * 8;
  const bf16* ga0 = A  + (size_t)(blockIdx.y*128 + wid*32 + srow) * K + scol;
  const bf16* gg0 = Wg + (size_t)(blockIdx.x*128 + wid*32 + srow) * K + scol;
  const bf16* gu0 = Wu + (size_t)(blockIdx.x*128 + wid*32 + srow) * K + scol;
  bf16* lA0 = As + wid*1024; bf16* lG0 = Gs + wid*1024; bf16* lU0 = Us + wid*1024;
  f32x4 accg[4][4], accu[4][4];
  #pragma unroll
  for (int i = 0; i < 4; ++i)
    #pragma unroll
    for (int j = 0; j < 4; ++j){
      accg[i][j] = (f32x4){0.f,0.f,0.f,0.f};
      accu[i][j] = (f32x4){0.f,0.f,0.f,0.f};
    }
  for (int k0 = 0; k0 < K; k0 += 32){
    __syncthreads();
    GLOAD_LDS16(ga0 + k0, lA0);
    GLOAD_LDS16(ga0 + (size_t)16*K + k0, lA0 + 512);
    GLOAD_LDS16(gg0 + k0, lG0);
    GLOAD_LDS16(gg0 + (size_t)16*K + k0, lG0 + 512);
    GLOAD_LDS16(gu0 + k0, lU0);
    GLOAD_LDS16(gu0 + (size_t)16*K + k0, lU0 + 512);
    __syncthreads();
    bf16x8 af[4], gf[4], uf[4];
    #pragma unroll
    for (int i = 0; i < 4; ++i)
      af[i] = *(const bf16x8*)(As + (wm + i*16 + r16)*32 + g8*8);
    #pragma unroll
    for (int j = 0; j < 4; ++j){
      gf[j] = *(const bf16x8*)(Gs + (wn + j*16 + r16)*32 + g8*8);
      uf[j] = *(const bf16x8*)(Us + (wn + j*16 + r16)*32 + g8*8);
    }
    #pragma unroll
    for (int i = 0; i < 4; ++i)
      #pragma unroll
      for (int j = 0; j < 4; ++j){
        accg[i][j] = __builtin_amdgcn_mfma_f32_16x16x32_bf16(af[i], gf[j], accg[i][j], 0, 0, 0);
        accu[i][j] = __builtin_amdgcn_mfma_f32_16x16x32_bf16(af[i], uf[j], accu[i][j], 0, 0, 0);
      }
  }
  #pragma unroll
  for (int i = 0; i < 4; ++i){
    int row = blockIdx.y*128 + wm + i*16 + g8*4;
    #pragma unroll
    for (int j = 0; j < 4; ++j){
      int col = blockIdx.x*128 + wn + j*16 + r16;
      #pragma unroll
      for (int r = 0; r < 4; ++r){
        float g = accg[i][j][r], u = accu[i][j][r];
        act[(size_t)(row + r) * FFNHID + col] = __float2bfloat16(siluf(g) * u);
      }
    }
  }
}

// down GEMM with fused final residual: out = x2 + mscale * (A @ W^T)
__global__ __launch_bounds__(256) void k_gemm_down(
    const bf16* __restrict__ A, const bf16* __restrict__ W,
    const float* __restrict__ x2, const float* __restrict__ mscale,
    float* __restrict__ out, int K)
{
  __shared__ __align__(16) bf16 As[128*32];
  __shared__ __align__(16) bf16 Ws[128*32];
  f32x4 acc[4][4];
  #pragma unroll
  for (int i = 0; i < 4; ++i)
    #pragma unroll
    for (int j = 0; j < 4; ++j) acc[i][j] = (f32x4){0.f,0.f,0.f,0.f};
  gemm_mainloop(A + (size_t)(blockIdx.y*128)*K, W + (size_t)(blockIdx.x*128)*K,
                K, As, Ws, acc);
  int tid = threadIdx.x, lane = tid & 63, wid = tid >> 6;
  int wm = (wid >> 1) * 64, wn = (wid & 1) * 64;
  int r16 = lane & 15, g8 = lane >> 4;
  #pragma unroll
  for (int i = 0; i < 4; ++i){
    int row = blockIdx.y*128 + wm + i*16 + g8*4;
    #pragma unroll
    for (int j = 0; j < 4; ++j){
      int col = blockIdx.x*128 + wn + j*16 + r16;
      #pragma unroll
      for (int r = 0; r < 4; ++r){
        size_t o = (size_t)(row + r) * DMODEL + col;
        out[o] = x2[o] + mscale[col] * acc[i][j][r];
      }
    }
  }
}

// fused causal conv4 + bias + silu (cols [0,2176)) and dt/softplus path (cols [2176,2208))
__global__ __launch_bounds__(256) void k_convdt(
    const float* __restrict__ xbcdt, const float* __restrict__ cw,
    const float* __restrict__ cb, const float* __restrict__ dtb,
    const float* __restrict__ alog, float* __restrict__ xbc,
    float* __restrict__ dtv, float* __restrict__ lav)
{
  int idx = blockIdx.x * 256 + threadIdx.x;
  if (idx >= LSEQ * 2208) return;
  int l = idx / 2208, c = idx - l * 2208;
  if (c < CONVDIM){
    float acc = cb[c];
    #pragma unroll
    for (int k = 0; k < 4; ++k){
      int t = l + k - 3;
      if (t >= 0) acc = fmaf(xbcdt[(size_t)t * XBCDT_W + c], cw[c*4 + k], acc);
    }
    xbc[(size_t)l * CONVDIM + c] = siluf(acc);
  } else {
    int h = c - CONVDIM;
    float raw = xbcdt[(size_t)l * XBCDT_W + c] + dtb[h];
    float d = (raw > 20.f) ? raw : log1pf(expf(raw));
    dtv[l * NHEADS + h] = d;
    lav[l * NHEADS + h] = -expf(alog[h]) * d;
  }
}

// chunked SSD pass A: per (head,chunk) T[p][n] = sum_j prod_{r>j}(a_r)*dt_j*x[j,p]*B[j,n]
__global__ __launch_bounds__(256) void k_scanA(
    const float* __restrict__ xbc, const float* __restrict__ dtv,
    const float* __restrict__ lav, float* __restrict__ T, float* __restrict__ ctot)
{
  __shared__ float sB[4096];
  __shared__ float sx[4096];
  __shared__ float sla[64], sdt[64], sa[64];
  int h = blockIdx.x >> 5, c = blockIdx.x & 31;
  int tid = threadIdx.x, t0 = c * 64;
  if (tid < 64){
    sla[tid] = lav[(size_t)(t0 + tid) * NHEADS + h];
    sdt[tid] = dtv[(size_t)(t0 + tid) * NHEADS + h];
  }
  for (int idx = tid; idx < 4096; idx += 256){
    int j = idx >> 6, n = idx & 63;
    size_t rb = (size_t)(t0 + j) * CONVDIM;
    sB[idx] = xbc[rb + DINNER + n];
    sx[idx] = xbc[rb + h * HEADDIM + n];
  }
  __syncthreads();
  if (tid < 64) sa[tid] = expf(sla[tid]);
  __syncthreads();
  int p = tid >> 2, n0 = (tid & 3) << 4;
  float acc[16];
  #pragma unroll
  for (int nn = 0; nn < 16; ++nn) acc[nn] = 0.f;
  float w = 1.f;
  for (int j = 63; j >= 0; --j){
    float cw = w * sdt[j] * sx[j*64 + p];
    #pragma unroll
    for (int nn = 0; nn < 16; ++nn) acc[nn] = fmaf(cw, sB[j*64 + n0 + nn], acc[nn]);
    w *= sa[j];
  }
  size_t ob = (size_t)blockIdx.x * 4096 + (size_t)p * 64 + n0;
  #pragma unroll
  for (int nn = 0; nn < 16; ++nn) T[ob + nn] = acc[nn];
  if (tid == 0) ctot[blockIdx.x] = w;
}

// pass B: sequential state recurrence over chunks; stores S_in in place of T
__global__ __launch_bounds__(256) void k_scanB(float* __restrict__ T, const float* __restrict__ ctot)
{
  int h = blockIdx.x >> 3, e = blockIdx.x & 7;
  int tid = threadIdx.x;
  size_t off = (size_t)e * 512 + tid * 2;
  float s0 = 0.f, s1 = 0.f;
  for (int c = 0; c < 32; ++c){
    float ct = ctot[h * 32 + c];
    size_t base = (size_t)(h * 32 + c) * 4096 + off;
    float2 tv = *(const float2*)&T[base];
    *(float2*)&T[base] = make_float2(s0, s1);
    s0 = fmaf(ct, s0, tv.x);
    s1 = fmaf(ct, s1, tv.y);
  }
}

// pass C: y[i,p] = intra(masked CB^T @ dt*x) + prod_a * (C @ S_in^T) + D*x
__global__ __launch_bounds__(256) void k_scanC(
    const float* __restrict__ xbc, const float* __restrict__ Sin,
    const float* __restrict__ dtv, const float* __restrict__ lav,
    const float* __restrict__ Dp, float* __restrict__ y)
{
  __shared__ float sC[4096];
  __shared__ float sBG[4096];   // B, then overwritten with G = C@B^T
  __shared__ float sS[4096];
  __shared__ bf16 sx[4096];
  __shared__ float sla[64], sdt[64], sa[64];
  int h = blockIdx.x >> 5, c = blockIdx.x & 31;
  int tid = threadIdx.x, t0 = c * 64;
  if (tid < 64){
    sla[tid] = lav[(size_t)(t0 + tid) * NHEADS + h];
    sdt[tid] = dtv[(size_t)(t0 + tid) * NHEADS + h];
  }
  for (int idx = tid; idx < 4096; idx += 256){
    int j = idx >> 6, n = idx & 63;
    size_t rb = (size_t)(t0 + j) * CONVDIM;
    sBG[idx] = xbc[rb + DINNER + n];
    sC[idx]  = xbc[rb + DINNER + DSTATE + n];
    sx[idx]  = __float2bfloat16(xbc[rb + h * HEADDIM + n]);
    sS[idx]  = Sin[(size_t)blockIdx.x * 4096 + idx];
  }
  __syncthreads();
  if (tid < 64) sa[tid] = expf(sla[tid]);
  __syncthreads();
  int i = tid >> 2, q0 = (tid & 3) << 4;
  float g[16];
  #pragma unroll
  for (int jj = 0; jj < 16; ++jj) g[jj] = 0.f;
  for (int n = 0; n < 64; ++n){
    float cin = sC[i*64 + n];
    #pragma unroll
    for (int jj = 0; jj < 16; ++jj) g[jj] = fmaf(cin, sBG[(q0 + jj)*64 + n], g[jj]);
  }
  __syncthreads();
  #pragma unroll
  for (int jj = 0; jj < 16; ++jj) sBG[i*64 + q0 + jj] = g[jj];
  __syncthreads();
  float accI[16];
  #pragma unroll
  for (int pp = 0; pp < 16; ++pp) accI[pp] = 0.f;
  float w = 1.f;
  for (int j = i; j >= 0; --j){
    float coef = w * sBG[i*64 + j] * sdt[j];
    #pragma unroll
    for (int pp = 0; pp < 16; ++pp)
      accI[pp] = fmaf(coef, __bfloat162float(sx[j*64 + q0 + pp]), accI[pp]);
    w *= sa[j];
  }
  float accS[16];
  #pragma unroll
  for (int pp = 0; pp < 16; ++pp) accS[pp] = 0.f;
  for (int n = 0; n < 64; ++n){
    float cin = sC[i*64 + n];
    #pragma unroll
    for (int pp = 0; pp < 16; ++pp)
      accS[pp] = fmaf(cin, sS[(q0 + pp)*64 + n], accS[pp]);
  }
  float Dh = Dp[h];
  size_t yb = (size_t)(t0 + i) * DINNER + h * HEADDIM + q0;
  #pragma unroll
  for (int pp = 0; pp < 16; ++pp)
    y[yb + pp] = accI[pp] + w * accS[pp] + Dh * __bfloat162float(sx[i*64 + q0 + pp]);
}

// yn = bf16(rms(y * silu(z)) * mnorm_w)
__global__ __launch_bounds__(256) void k_gate_rms(
    const float* __restrict__ y, const float* __restrict__ zbuf,
    const float* __restrict__ mw, bf16* __restrict__ yn)
{
  int row = blockIdx.x, tid = threadIdx.x;
  const float4* yr = (const float4*)(y    + (size_t)row * DINNER);
  const float4* zr = (const float4*)(zbuf + (size_t)row * DINNER);
  float4 v[2]; float ss = 0.f;
  #pragma unroll
  for (int i = 0; i < 2; ++i){
    int d4 = tid + i * 256;
    float4 yv = yr[d4], zv = zr[d4];
    float4 g;
    g.x = yv.x * siluf(zv.x); g.y = yv.y * siluf(zv.y);
    g.z = yv.z * siluf(zv.z); g.w = yv.w * siluf(zv.w);
    v[i] = g;
    ss += g.x*g.x + g.y*g.y + g.z*g.z + g.w*g.w;
  }
  ss = block_reduce_sum_256(ss);
  float inv = rsqrtf(ss / (float)DINNER + 1e-6f);
  #pragma unroll
  for (int i = 0; i < 2; ++i){
    int d4 = tid + i * 256;
    float4 mv = ((const float4*)mw)[d4];
    ushort4 o;
    o.x = bf16bits(v[i].x*inv*mv.x); o.y = bf16bits(v[i].y*inv*mv.y);
    o.z = bf16bits(v[i].z*inv*mv.z); o.w = bf16bits(v[i].w*inv*mv.w);
    *(ushort4*)(yn + (size_t)row * DINNER + d4*4) = o;
  }
}

// x2 = xres + ssm_scale*yo ; hb = bf16(rms(x2)*ffn_norm_w)
__global__ __launch_bounds__(256) void k_res_rms(
    const float* __restrict__ xres, const float* __restrict__ yo,
    const float* __restrict__ scale, const float* __restrict__ nw,
    float* __restrict__ x2, bf16* __restrict__ hb)
{
  int row = blockIdx.x, tid = threadIdx.x;
  float4 xv = ((const float4*)(xres + (size_t)row * DMODEL))[tid];
  float4 yv = ((const float4*)(yo   + (size_t)row * DMODEL))[tid];
  float4 sv = ((const float4*)scale)[tid];
  float4 a;
  a.x = xv.x + sv.x*yv.x; a.y = xv.y + sv.y*yv.y;
  a.z = xv.z + sv.z*yv.z; a.w = xv.w + sv.w*yv.w;
  ((float4*)(x2 + (size_t)row * DMODEL))[tid] = a;
  float ss = a.x*a.x + a.y*a.y + a.z*a.z + a.w*a.w;
  ss = block_reduce_sum_256(ss);
  float inv = rsqrtf(ss / (float)DMODEL + 1e-6f);
  float4 nv = ((const float4*)nw)[tid];
  ushort4 o;
  o.x = bf16bits(a.x*inv*nv.x); o.y = bf16bits(a.y*inv*nv.y);
  o.z = bf16bits(a.z*inv*nv.z); o.w = bf16bits(a.w*inv*nv.w);
  *(ushort4*)(hb + (size_t)row * DMODEL + tid*4) = o;
}

extern "C" void kernel_launch(void* const* d_in, const int* in_sizes, int n_in,
                              void* d_out, int out_size, void* d_ws, size_t ws_size,
                              hipStream_t stream)
{
  const float* x      = (const float*)d_in[0];
  const float* x0     = (const float*)d_in[1];
  const float* rm     = (const float*)d_in[3];
  const float* sscale = (const float*)d_in[4];
  const float* mscale = (const float*)d_in[5];
  const float* snw    = (const float*)d_in[6];
  const float* fnw    = (const float*)d_in[7];
  const float* win    = (const float*)d_in[8];
  const float* cw     = (const float*)d_in[9];
  const float* cb     = (const float*)d_in[10];
  const float* dtb    = (const float*)d_in[11];
  const float* alog   = (const float*)d_in[12];
  const float* Dp     = (const float*)d_in[13];
  const float* mnw    = (const float*)d_in[14];
  const float* wout   = (const float*)d_in[15];
  const float* wgu    = (const float*)d_in[16];
  const float* wdn    = (const float*)d_in[17];
  float* out = (float*)d_out;

  // Workspace layout (MiB offsets), lifetime-overlapped; peak 114 MiB + 4KB.
  const size_t MB = 1024ull * 1024ull;
  char* ws = (char*)d_ws;
  bf16*  winb  = (bf16*) (ws + 0*MB);
  bf16*  act   = (bf16*) (ws + 0*MB);
  bf16*  woutb = (bf16*) (ws + 13*MB);
  bf16*  wgub  = (bf16*) (ws + 17*MB);
  bf16*  wdnb  = (bf16*) (ws + 29*MB);
  float* xres  = (float*)(ws + 35*MB);
  bf16*  u     = (bf16*) (ws + 43*MB);
  float* dtv   = (float*)(ws + 43*MB);
  float* lav   = (float*)(ws + 43*MB + 256*1024);
  bf16*  hb    = (bf16*) (ws + 43*MB);
  float* zbuf  = (float*)(ws + 47*MB);
  float* x2    = (float*)(ws + 47*MB);
  float* xbcdt = (float*)(ws + 63*MB);
  float* yb    = (float*)(ws + 63*MB);
  float* xbc   = (float*)(ws + 81*MB);
  float* yo    = (float*)(ws + 81*MB);
  float* T     = (float*)(ws + 98*MB);
  bf16*  yn    = (bf16*) (ws + 98*MB);
  float* ctot  = (float*)(ws + 114*MB);

  dim3 blk(256);
  k_cast_all<<<15616, blk, 0, stream>>>(win, wout, wgu, wdn, winb, woutb, wgub, wdnb);
  k_mix_rms<<<LSEQ, blk, 0, stream>>>(x, x0, rm, snw, xres, u);
  k_gemm_inproj<<<dim3(34,16), blk, 0, stream>>>(u, winb, zbuf, xbcdt);
  k_convdt<<<(LSEQ*2208 + 255)/256, blk, 0, stream>>>(xbcdt, cw, cb, dtb, alog, xbc, dtv, lav);
  k_scanA<<<NHEADS*32, blk, 0, stream>>>(xbc, dtv, lav, T, ctot);
  k_scanB<<<NHEADS*8, blk, 0, stream>>>(T, ctot);
  k_scanC<<<NHEADS*32, blk, 0, stream>>>(xbc, T, dtv, lav, Dp, yb);
  k_gate_rms<<<LSEQ, blk, 0, stream>>>(yb, zbuf, mnw, yn);
  k_gemm_plain<<<dim3(8,16), blk, 0, stream>>>(yn, woutb, yo, DINNER, DMODEL);
  k_res_rms<<<LSEQ, blk, 0, stream>>>(xres, yo, sscale, fnw, x2, hb);
  k_gemm_ffn<<<dim3(24,16), blk, 0, stream>>>(hb, wgub, wgub + (size_t)FFNHID*DMODEL, act, DMODEL);
  k_gemm_down<<<dim3(8,16), blk, 0, stream>>>(act, wdnb, x2, mscale, out, FFNHID);
}

// Round 4
// 325.771 us; speedup vs baseline: 5.0579x; 1.2675x over previous
//
#include <hip/hip_runtime.h>
#include <hip/hip_bf16.h>
#include <math.h>

#define LSEQ 2048
#define DMODEL 1024
#define DINNER 2048
#define NHEADS 32
#define HEADDIM 64
#define DSTATE 64
#define CONVDIM 2176     // DINNER + 2*DSTATE
#define XBCDT_W 2304     // padded width of (xBC | dt) block
#define FFNHID 3072

typedef float f32x4 __attribute__((ext_vector_type(4)));
typedef __bf16 bf16x8 __attribute__((ext_vector_type(8)));
typedef __hip_bfloat16 bf16;

__device__ __forceinline__ float siluf(float x){ return x / (1.0f + expf(-x)); }

// direct global->LDS DMA, 16B per lane; LDS dest is wave-uniform base + lane*16
#define GLOAD_LDS16(gp, lp) __builtin_amdgcn_global_load_lds( \
    (const __attribute__((address_space(1))) void*)(gp), \
    (__attribute__((address_space(3))) void*)(lp), 16, 0, 0)

__device__ __forceinline__ float block_reduce_sum_256(float v){
  #pragma unroll
  for (int o = 32; o > 0; o >>= 1) v += __shfl_down(v, o, 64);
  __shared__ float sh[4];
  int lane = threadIdx.x & 63;
  int w = threadIdx.x >> 6;
  if (lane == 0) sh[w] = v;
  __syncthreads();
  return sh[0] + sh[1] + sh[2] + sh[3];
}

__device__ __forceinline__ ushort bf16bits(float f){
  __hip_bfloat16 h = __float2bfloat16(f);
  return *reinterpret_cast<ushort*>(&h);
}

// all 4 weight casts in one dispatch, float4 -> 4x bf16 per thread
__global__ __launch_bounds__(256) void k_cast_all(
    const float* __restrict__ w0, const float* __restrict__ w1,
    const float* __restrict__ w2, const float* __restrict__ w3,
    bf16* __restrict__ d0, bf16* __restrict__ d1,
    bf16* __restrict__ d2, bf16* __restrict__ d3)
{
  int idx = blockIdx.x * 256 + threadIdx.x;   // float4 index, total 3997696
  const float* s; bf16* d; int valid;
  if (idx < 1114112)              { s = w0; d = d0; valid = 1089536; }           // winb pad->4352 rows
  else if (idx < 1638400)         { idx -= 1114112; s = w1; d = d1; valid = 524288; }
  else if (idx < 3211264)         { idx -= 1638400; s = w2; d = d2; valid = 1572864; }
  else                            { idx -= 3211264; s = w3; d = d3; valid = 786432; }
  float4 v = (idx < valid) ? *(const float4*)(s + (size_t)idx * 4)
                           : make_float4(0.f, 0.f, 0.f, 0.f);
  ushort4 r;
  r.x = bf16bits(v.x); r.y = bf16bits(v.y); r.z = bf16bits(v.z); r.w = bf16bits(v.w);
  *(ushort4*)(d + (size_t)idx * 4) = r;
}

// x_res = rm0*x + rm1*x0 ; u = bf16(rms(x_res)*ssm_norm_w)
__global__ __launch_bounds__(256) void k_mix_rms(
    const float* __restrict__ x, const float* __restrict__ x0,
    const float* __restrict__ rm, const float* __restrict__ nw,
    float* __restrict__ xres, bf16* __restrict__ u)
{
  int row = blockIdx.x, tid = threadIdx.x;
  float4 xv  = ((const float4*)(x  + (size_t)row * DMODEL))[tid];
  float4 x0v = ((const float4*)(x0 + (size_t)row * DMODEL))[tid];
  float4 r0 = ((const float4*)rm)[tid];
  float4 r1 = ((const float4*)(rm + DMODEL))[tid];
  float4 a;
  a.x = r0.x*xv.x + r1.x*x0v.x; a.y = r0.y*xv.y + r1.y*x0v.y;
  a.z = r0.z*xv.z + r1.z*x0v.z; a.w = r0.w*xv.w + r1.w*x0v.w;
  ((float4*)(xres + (size_t)row * DMODEL))[tid] = a;
  float ss = a.x*a.x + a.y*a.y + a.z*a.z + a.w*a.w;
  ss = block_reduce_sum_256(ss);
  float inv = rsqrtf(ss / (float)DMODEL + 1e-6f);
  float4 nv = ((const float4*)nw)[tid];
  ushort4 o;
  o.x = bf16bits(a.x*inv*nv.x); o.y = bf16bits(a.y*inv*nv.y);
  o.z = bf16bits(a.z*inv*nv.z); o.w = bf16bits(a.w*inv*nv.w);
  *(ushort4*)(u + (size_t)row * DMODEL + tid*4) = o;
}

// ---------- double-buffered bf16 MFMA GEMM mainloop (2-phase prefetch) ----------
// 128x128 tile, BK=32, 4 waves (2x2), wave = 64x64 = 4x4 frags of 16x16x32.
// LDS [2][128][32] per matrix, staged by global_load_lds w=16.
// XOR swizzle (slot ^= row&3) applied on the GLOBAL source address (DMA writes
// linearly) and on the read side -> 8-way b128 conflict becomes 4-way.
// Loop: STAGE(next) ; ds_read+MFMA(cur) ; __syncthreads (drains vmcnt+lgkm).
__device__ __forceinline__ void gemm_mainloop_db(
    const bf16* __restrict__ A, const bf16* __restrict__ W,
    int ld, int Klen, bf16* As, bf16* Ws, f32x4 acc[4][4])
{
  int tid = threadIdx.x;
  int lane = tid & 63, wid = tid >> 6;
  int wm = (wid >> 1) * 64, wn = (wid & 1) * 64;
  int r16 = lane & 15, g8 = lane >> 4;
  int srow = lane >> 2;
  int scol = ((lane & 3) ^ (srow & 3)) * 8;     // pre-swizzled source slot
  const bf16* ga0 = A + (size_t)(wid*32 + srow) * ld + scol;
  const bf16* ga1 = ga0 + (size_t)16 * ld;
  const bf16* gw0 = W + (size_t)(wid*32 + srow) * ld + scol;
  const bf16* gw1 = gw0 + (size_t)16 * ld;
  bf16* lA = As + wid*1024;
  bf16* lW = Ws + wid*1024;
  GLOAD_LDS16(ga0, lA);
  GLOAD_LDS16(ga1, lA + 512);
  GLOAD_LDS16(gw0, lW);
  GLOAD_LDS16(gw1, lW + 512);
  __syncthreads();
  int cur = 0;
  int s4 = (r16 & 3) * 8;                        // read-side swizzle
  for (int k0 = 0; k0 < Klen; k0 += 32){
    if (k0 + 32 < Klen){
      int nb = (cur ^ 1) * 4096;
      GLOAD_LDS16(ga0 + k0 + 32, As + nb + wid*1024);
      GLOAD_LDS16(ga1 + k0 + 32, As + nb + wid*1024 + 512);
      GLOAD_LDS16(gw0 + k0 + 32, Ws + nb + wid*1024);
      GLOAD_LDS16(gw1 + k0 + 32, Ws + nb + wid*1024 + 512);
    }
    int cb = cur * 4096;
    bf16x8 af[4], bfr[4];
    #pragma unroll
    for (int i = 0; i < 4; ++i)
      af[i] = *(const bf16x8*)(As + cb + (wm + i*16 + r16)*32 + (g8*8 ^ s4));
    #pragma unroll
    for (int j = 0; j < 4; ++j)
      bfr[j] = *(const bf16x8*)(Ws + cb + (wn + j*16 + r16)*32 + (g8*8 ^ s4));
    #pragma unroll
    for (int i = 0; i < 4; ++i)
      #pragma unroll
      for (int j = 0; j < 4; ++j)
        acc[i][j] = __builtin_amdgcn_mfma_f32_16x16x32_bf16(af[i], bfr[j], acc[i][j], 0, 0, 0);
    __syncthreads();
    cur ^= 1;
  }
}

// in_proj: one dispatch, block cols [0,16) -> zbuf (N=2048), [16,34) -> xbcdt (N=2304)
__global__ __launch_bounds__(256) void k_gemm_inproj(
    const bf16* __restrict__ A, const bf16* __restrict__ Wfull,
    float* __restrict__ zbuf, float* __restrict__ xbcdt)
{
  __shared__ __align__(16) bf16 As[2*4096];
  __shared__ __align__(16) bf16 Ws[2*4096];
  int bx = blockIdx.x, by = blockIdx.y;
  f32x4 acc[4][4];
  #pragma unroll
  for (int i = 0; i < 4; ++i)
    #pragma unroll
    for (int j = 0; j < 4; ++j) acc[i][j] = (f32x4){0.f,0.f,0.f,0.f};
  gemm_mainloop_db(A + (size_t)(by*128)*DMODEL, Wfull + (size_t)(bx*128)*DMODEL,
                   DMODEL, DMODEL, As, Ws, acc);
  int tid = threadIdx.x, lane = tid & 63, wid = tid >> 6;
  int wm = (wid >> 1) * 64, wn = (wid & 1) * 64;
  int r16 = lane & 15, g8 = lane >> 4;
  float* Cp; int ldc, col0;
  if (bx < 16){ Cp = zbuf;  ldc = DINNER;  col0 = bx*128; }
  else        { Cp = xbcdt; ldc = XBCDT_W; col0 = (bx-16)*128; }
  #pragma unroll
  for (int i = 0; i < 4; ++i){
    int row = by*128 + wm + i*16 + g8*4;
    #pragma unroll
    for (int j = 0; j < 4; ++j){
      int col = col0 + wn + j*16 + r16;
      #pragma unroll
      for (int r = 0; r < 4; ++r)
        Cp[(size_t)(row + r) * ldc + col] = acc[i][j][r];
    }
  }
}

// split-K GEMM: P[z][M][N] partial over K range [z*Khalf, (z+1)*Khalf)
__global__ __launch_bounds__(256) void k_gemm_splitk(
    const bf16* __restrict__ A, const bf16* __restrict__ W,
    float* __restrict__ P, int Kfull, int Khalf, int N)
{
  __shared__ __align__(16) bf16 As[2*4096];
  __shared__ __align__(16) bf16 Ws[2*4096];
  f32x4 acc[4][4];
  #pragma unroll
  for (int i = 0; i < 4; ++i)
    #pragma unroll
    for (int j = 0; j < 4; ++j) acc[i][j] = (f32x4){0.f,0.f,0.f,0.f};
  int z = blockIdx.z;
  gemm_mainloop_db(A + (size_t)(blockIdx.y*128)*Kfull + z*Khalf,
                   W + (size_t)(blockIdx.x*128)*Kfull + z*Khalf,
                   Kfull, Khalf, As, Ws, acc);
  float* Pz = P + (size_t)z * LSEQ * N;
  int tid = threadIdx.x, lane = tid & 63, wid = tid >> 6;
  int wm = (wid >> 1) * 64, wn = (wid & 1) * 64;
  int r16 = lane & 15, g8 = lane >> 4;
  #pragma unroll
  for (int i = 0; i < 4; ++i){
    int row = blockIdx.y*128 + wm + i*16 + g8*4;
    #pragma unroll
    for (int j = 0; j < 4; ++j){
      int col = blockIdx.x*128 + wn + j*16 + r16;
      #pragma unroll
      for (int r = 0; r < 4; ++r)
        Pz[(size_t)(row + r) * N + col] = acc[i][j][r];
    }
  }
}

// FFN gate_up with fused SwiGLU epilogue: act = bf16(silu(A@Wg^T) * (A@Wu^T))
__global__ __launch_bounds__(256) void k_gemm_ffn(
    const bf16* __restrict__ A, const bf16* __restrict__ Wg, const bf16* __restrict__ Wu,
    bf16* __restrict__ act, int K)
{
  __shared__ __align__(16) bf16 As[2*4096];
  __shared__ __align__(16) bf16 Gs[2*4096];
  __shared__ __align__(16) bf16 Us[2*4096];
  int tid = threadIdx.x;
  int lane = tid & 63, wid = tid >> 6;
  int wm = (wid >> 1) * 64, wn = (wid & 1) * 64;
  int r16 = lane & 15, g8 = lane >> 4;
  int srow = lane >> 2;
  int scol = ((lane & 3) ^ (srow & 3)) * 8;
  const bf16* ga0 = A  + (size_t)(blockIdx.y*128 + wid*32 + srow) * K + scol;
  const bf16* gg0 = Wg + (size_t)(blockIdx.x*128 + wid*32 + srow) * K + scol;
  const bf16* gu0 = Wu + (size_t)(blockIdx.x*128 + wid*32 + srow) * K + scol;
  const bf16* ga1 = ga0 + (size_t)16*K;
  const bf16* gg1 = gg0 + (size_t)16*K;
  const bf16* gu1 = gu0 + (size_t)16*K;
  bf16* lA = As + wid*1024; bf16* lG = Gs + wid*1024; bf16* lU = Us + wid*1024;
  f32x4 accg[4][4], accu[4][4];
  #pragma unroll
  for (int i = 0; i < 4; ++i)
    #pragma unroll
    for (int j = 0; j < 4; ++j){
      accg[i][j] = (f32x4){0.f,0.f,0.f,0.f};
      accu[i][j] = (f32x4){0.f,0.f,0.f,0.f};
    }
  GLOAD_LDS16(ga0, lA); GLOAD_LDS16(ga1, lA + 512);
  GLOAD_LDS16(gg0, lG); GLOAD_LDS16(gg1, lG + 512);
  GLOAD_LDS16(gu0, lU); GLOAD_LDS16(gu1, lU + 512);
  __syncthreads();
  int cur = 0;
  int s4 = (r16 & 3) * 8;
  for (int k0 = 0; k0 < K; k0 += 32){
    if (k0 + 32 < K){
      int nb = (cur ^ 1) * 4096;
      GLOAD_LDS16(ga0 + k0 + 32, As + nb + wid*1024);
      GLOAD_LDS16(ga1 + k0 + 32, As + nb + wid*1024 + 512);
      GLOAD_LDS16(gg0 + k0 + 32, Gs + nb + wid*1024);
      GLOAD_LDS16(gg1 + k0 + 32, Gs + nb + wid*1024 + 512);
      GLOAD_LDS16(gu0 + k0 + 32, Us + nb + wid*1024);
      GLOAD_LDS16(gu1 + k0 + 32, Us + nb + wid*1024 + 512);
    }
    int cb = cur * 4096;
    bf16x8 af[4], gf[4], uf[4];
    #pragma unroll
    for (int i = 0; i < 4; ++i)
      af[i] = *(const bf16x8*)(As + cb + (wm + i*16 + r16)*32 + (g8*8 ^ s4));
    #pragma unroll
    for (int j = 0; j < 4; ++j){
      gf[j] = *(const bf16x8*)(Gs + cb + (wn + j*16 + r16)*32 + (g8*8 ^ s4));
      uf[j] = *(const bf16x8*)(Us + cb + (wn + j*16 + r16)*32 + (g8*8 ^ s4));
    }
    #pragma unroll
    for (int i = 0; i < 4; ++i)
      #pragma unroll
      for (int j = 0; j < 4; ++j){
        accg[i][j] = __builtin_amdgcn_mfma_f32_16x16x32_bf16(af[i], gf[j], accg[i][j], 0, 0, 0);
        accu[i][j] = __builtin_amdgcn_mfma_f32_16x16x32_bf16(af[i], uf[j], accu[i][j], 0, 0, 0);
      }
    __syncthreads();
    cur ^= 1;
  }
  #pragma unroll
  for (int i = 0; i < 4; ++i){
    int row = blockIdx.y*128 + wm + i*16 + g8*4;
    #pragma unroll
    for (int j = 0; j < 4; ++j){
      int col = blockIdx.x*128 + wn + j*16 + r16;
      #pragma unroll
      for (int r = 0; r < 4; ++r){
        float g = accg[i][j][r], u = accu[i][j][r];
        act[(size_t)(row + r) * FFNHID + col] = __float2bfloat16(siluf(g) * u);
      }
    }
  }
}

// fused causal conv4 + bias + silu (cols [0,2176)) and dt/softplus path (cols [2176,2208))
__global__ __launch_bounds__(256) void k_convdt(
    const float* __restrict__ xbcdt, const float* __restrict__ cw,
    const float* __restrict__ cb, const float* __restrict__ dtb,
    const float* __restrict__ alog, float* __restrict__ xbc,
    float* __restrict__ dtv, float* __restrict__ lav)
{
  int idx = blockIdx.x * 256 + threadIdx.x;
  if (idx >= LSEQ * 2208) return;
  int l = idx / 2208, c = idx - l * 2208;
  if (c < CONVDIM){
    float acc = cb[c];
    #pragma unroll
    for (int k = 0; k < 4; ++k){
      int t = l + k - 3;
      if (t >= 0) acc = fmaf(xbcdt[(size_t)t * XBCDT_W + c], cw[c*4 + k], acc);
    }
    xbc[(size_t)l * CONVDIM + c] = siluf(acc);
  } else {
    int h = c - CONVDIM;
    float raw = xbcdt[(size_t)l * XBCDT_W + c] + dtb[h];
    float d = (raw > 20.f) ? raw : log1pf(expf(raw));
    dtv[l * NHEADS + h] = d;
    lav[l * NHEADS + h] = -expf(alog[h]) * d;
  }
}

// chunked SSD pass A: per (head,chunk) T[p][n] = sum_j prod_{r>j}(a_r)*dt_j*x[j,p]*B[j,n]
__global__ __launch_bounds__(256) void k_scanA(
    const float* __restrict__ xbc, const float* __restrict__ dtv,
    const float* __restrict__ lav, float* __restrict__ T, float* __restrict__ ctot)
{
  __shared__ float sB[4096];
  __shared__ float sx[4096];
  __shared__ float sla[64], sdt[64], sa[64];
  int h = blockIdx.x >> 5, c = blockIdx.x & 31;
  int tid = threadIdx.x, t0 = c * 64;
  if (tid < 64){
    sla[tid] = lav[(size_t)(t0 + tid) * NHEADS + h];
    sdt[tid] = dtv[(size_t)(t0 + tid) * NHEADS + h];
  }
  for (int idx = tid; idx < 4096; idx += 256){
    int j = idx >> 6, n = idx & 63;
    size_t rb = (size_t)(t0 + j) * CONVDIM;
    sB[idx] = xbc[rb + DINNER + n];
    sx[idx] = xbc[rb + h * HEADDIM + n];
  }
  __syncthreads();
  if (tid < 64) sa[tid] = expf(sla[tid]);
  __syncthreads();
  int p = tid >> 2, n0 = (tid & 3) << 4;
  float acc[16];
  #pragma unroll
  for (int nn = 0; nn < 16; ++nn) acc[nn] = 0.f;
  float w = 1.f;
  for (int j = 63; j >= 0; --j){
    float cw = w * sdt[j] * sx[j*64 + p];
    #pragma unroll
    for (int nn = 0; nn < 16; ++nn) acc[nn] = fmaf(cw, sB[j*64 + n0 + nn], acc[nn]);
    w *= sa[j];
  }
  size_t ob = (size_t)blockIdx.x * 4096 + (size_t)p * 64 + n0;
  #pragma unroll
  for (int nn = 0; nn < 16; ++nn) T[ob + nn] = acc[nn];
  if (tid == 0) ctot[blockIdx.x] = w;
}

// pass B: sequential state recurrence over chunks; stores S_in in place of T
__global__ __launch_bounds__(256) void k_scanB(float* __restrict__ T, const float* __restrict__ ctot)
{
  int h = blockIdx.x >> 3, e = blockIdx.x & 7;
  int tid = threadIdx.x;
  size_t off = (size_t)e * 512 + tid * 2;
  float s0 = 0.f, s1 = 0.f;
  for (int c = 0; c < 32; ++c){
    float ct = ctot[h * 32 + c];
    size_t base = (size_t)(h * 32 + c) * 4096 + off;
    float2 tv = *(const float2*)&T[base];
    *(float2*)&T[base] = make_float2(s0, s1);
    s0 = fmaf(ct, s0, tv.x);
    s1 = fmaf(ct, s1, tv.y);
  }
}

// pass C: y[i,p] = intra(masked CB^T @ dt*x) + prod_a * (C @ S_in^T) + D*x
__global__ __launch_bounds__(256) void k_scanC(
    const float* __restrict__ xbc, const float* __restrict__ Sin,
    const float* __restrict__ dtv, const float* __restrict__ lav,
    const float* __restrict__ Dp, float* __restrict__ y)
{
  __shared__ float sC[4096];
  __shared__ float sBG[4096];   // B, then overwritten with G = C@B^T
  __shared__ float sS[4096];
  __shared__ bf16 sx[4096];
  __shared__ float sla[64], sdt[64], sa[64];
  int h = blockIdx.x >> 5, c = blockIdx.x & 31;
  int tid = threadIdx.x, t0 = c * 64;
  if (tid < 64){
    sla[tid] = lav[(size_t)(t0 + tid) * NHEADS + h];
    sdt[tid] = dtv[(size_t)(t0 + tid) * NHEADS + h];
  }
  for (int idx = tid; idx < 4096; idx += 256){
    int j = idx >> 6, n = idx & 63;
    size_t rb = (size_t)(t0 + j) * CONVDIM;
    sBG[idx] = xbc[rb + DINNER + n];
    sC[idx]  = xbc[rb + DINNER + DSTATE + n];
    sx[idx]  = __float2bfloat16(xbc[rb + h * HEADDIM + n]);
    sS[idx]  = Sin[(size_t)blockIdx.x * 4096 + idx];
  }
  __syncthreads();
  if (tid < 64) sa[tid] = expf(sla[tid]);
  __syncthreads();
  int i = tid >> 2, q0 = (tid & 3) << 4;
  float g[16];
  #pragma unroll
  for (int jj = 0; jj < 16; ++jj) g[jj] = 0.f;
  for (int n = 0; n < 64; ++n){
    float cin = sC[i*64 + n];
    #pragma unroll
    for (int jj = 0; jj < 16; ++jj) g[jj] = fmaf(cin, sBG[(q0 + jj)*64 + n], g[jj]);
  }
  __syncthreads();
  #pragma unroll
  for (int jj = 0; jj < 16; ++jj) sBG[i*64 + q0 + jj] = g[jj];
  __syncthreads();
  float accI[16];
  #pragma unroll
  for (int pp = 0; pp < 16; ++pp) accI[pp] = 0.f;
  float w = 1.f;
  for (int j = i; j >= 0; --j){
    float coef = w * sBG[i*64 + j] * sdt[j];
    #pragma unroll
    for (int pp = 0; pp < 16; ++pp)
      accI[pp] = fmaf(coef, __bfloat162float(sx[j*64 + q0 + pp]), accI[pp]);
    w *= sa[j];
  }
  float accS[16];
  #pragma unroll
  for (int pp = 0; pp < 16; ++pp) accS[pp] = 0.f;
  for (int n = 0; n < 64; ++n){
    float cin = sC[i*64 + n];
    #pragma unroll
    for (int pp = 0; pp < 16; ++pp)
      accS[pp] = fmaf(cin, sS[(q0 + pp)*64 + n], accS[pp]);
  }
  float Dh = Dp[h];
  size_t yb = (size_t)(t0 + i) * DINNER + h * HEADDIM + q0;
  #pragma unroll
  for (int pp = 0; pp < 16; ++pp)
    y[yb + pp] = accI[pp] + w * accS[pp] + Dh * __bfloat162float(sx[i*64 + q0 + pp]);
}

// yn = bf16(rms(y * silu(z)) * mnorm_w)
__global__ __launch_bounds__(256) void k_gate_rms(
    const float* __restrict__ y, const float* __restrict__ zbuf,
    const float* __restrict__ mw, bf16* __restrict__ yn)
{
  int row = blockIdx.x, tid = threadIdx.x;
  const float4* yr = (const float4*)(y    + (size_t)row * DINNER);
  const float4* zr = (const float4*)(zbuf + (size_t)row * DINNER);
  float4 v[2]; float ss = 0.f;
  #pragma unroll
  for (int i = 0; i < 2; ++i){
    int d4 = tid + i * 256;
    float4 yv = yr[d4], zv = zr[d4];
    float4 g;
    g.x = yv.x * siluf(zv.x); g.y = yv.y * siluf(zv.y);
    g.z = yv.z * siluf(zv.z); g.w = yv.w * siluf(zv.w);
    v[i] = g;
    ss += g.x*g.x + g.y*g.y + g.z*g.z + g.w*g.w;
  }
  ss = block_reduce_sum_256(ss);
  float inv = rsqrtf(ss / (float)DINNER + 1e-6f);
  #pragma unroll
  for (int i = 0; i < 2; ++i){
    int d4 = tid + i * 256;
    float4 mv = ((const float4*)mw)[d4];
    ushort4 o;
    o.x = bf16bits(v[i].x*inv*mv.x); o.y = bf16bits(v[i].y*inv*mv.y);
    o.z = bf16bits(v[i].z*inv*mv.z); o.w = bf16bits(v[i].w*inv*mv.w);
    *(ushort4*)(yn + (size_t)row * DINNER + d4*4) = o;
  }
}

// x2 = xres + ssm_scale*(yo0+yo1) ; hb = bf16(rms(x2)*ffn_norm_w)
__global__ __launch_bounds__(256) void k_res_rms(
    const float* __restrict__ xres, const float* __restrict__ yo0,
    const float* __restrict__ yo1, const float* __restrict__ scale,
    const float* __restrict__ nw, float* __restrict__ x2, bf16* __restrict__ hb)
{
  int row = blockIdx.x, tid = threadIdx.x;
  float4 xv = ((const float4*)(xres + (size_t)row * DMODEL))[tid];
  float4 y0 = ((const float4*)(yo0  + (size_t)row * DMODEL))[tid];
  float4 y1 = ((const float4*)(yo1  + (size_t)row * DMODEL))[tid];
  float4 sv = ((const float4*)scale)[tid];
  float4 a;
  a.x = xv.x + sv.x*(y0.x+y1.x); a.y = xv.y + sv.y*(y0.y+y1.y);
  a.z = xv.z + sv.z*(y0.z+y1.z); a.w = xv.w + sv.w*(y0.w+y1.w);
  ((float4*)(x2 + (size_t)row * DMODEL))[tid] = a;
  float ss = a.x*a.x + a.y*a.y + a.z*a.z + a.w*a.w;
  ss = block_reduce_sum_256(ss);
  float inv = rsqrtf(ss / (float)DMODEL + 1e-6f);
  float4 nv = ((const float4*)nw)[tid];
  ushort4 o;
  o.x = bf16bits(a.x*inv*nv.x); o.y = bf16bits(a.y*inv*nv.y);
  o.z = bf16bits(a.z*inv*nv.z); o.w = bf16bits(a.w*inv*nv.w);
  *(ushort4*)(hb + (size_t)row * DMODEL + tid*4) = o;
}

// out = x2 + mscale*(d0+d1)   (float4)
__global__ __launch_bounds__(256) void k_final(
    const float* __restrict__ x2, const float* __restrict__ d0,
    const float* __restrict__ d1, const float* __restrict__ mscale,
    float* __restrict__ out)
{
  int i4 = blockIdx.x * 256 + threadIdx.x;     // 524288 float4s
  float4 xv = ((const float4*)x2)[i4];
  float4 a  = ((const float4*)d0)[i4];
  float4 b  = ((const float4*)d1)[i4];
  float4 mv = ((const float4*)mscale)[i4 & 255];
  float4 o;
  o.x = xv.x + mv.x*(a.x+b.x); o.y = xv.y + mv.y*(a.y+b.y);
  o.z = xv.z + mv.z*(a.z+b.z); o.w = xv.w + mv.w*(a.w+b.w);
  ((float4*)out)[i4] = o;
}

extern "C" void kernel_launch(void* const* d_in, const int* in_sizes, int n_in,
                              void* d_out, int out_size, void* d_ws, size_t ws_size,
                              hipStream_t stream)
{
  const float* x      = (const float*)d_in[0];
  const float* x0     = (const float*)d_in[1];
  const float* rm     = (const float*)d_in[3];
  const float* sscale = (const float*)d_in[4];
  const float* mscale = (const float*)d_in[5];
  const float* snw    = (const float*)d_in[6];
  const float* fnw    = (const float*)d_in[7];
  const float* win    = (const float*)d_in[8];
  const float* cw     = (const float*)d_in[9];
  const float* cb     = (const float*)d_in[10];
  const float* dtb    = (const float*)d_in[11];
  const float* alog   = (const float*)d_in[12];
  const float* Dp     = (const float*)d_in[13];
  const float* mnw    = (const float*)d_in[14];
  const float* wout   = (const float*)d_in[15];
  const float* wgu    = (const float*)d_in[16];
  const float* wdn    = (const float*)d_in[17];
  float* out = (float*)d_out;

  // Workspace (MiB offsets), lifetime-overlapped; peak 114 MiB + 4KB:
  //  [0,13)   winb -> act bf16
  //  [13,17)  woutb ; [17,29) wgub ; [29,35) wdnb
  //  [35,43)  xres
  //  [43,47)  u bf16 -> dt+la -> hb bf16
  //  [47,63)  zbuf (dead after gate_rms) -> x2 [47,55) ; dP0 [55,63)
  //  [63,81)  xbcdt -> yb [63,79) (dead after gate_rms) -> dP1 [63,71)
  //  [81,98)  xbc (dead after scanC) -> yoP [81,97)
  //  [98,114) T/Sin -> yn bf16 [98,106)
  //  [114]    ctot
  const size_t MB = 1024ull * 1024ull;
  char* ws = (char*)d_ws;
  bf16*  winb  = (bf16*) (ws + 0*MB);
  bf16*  act   = (bf16*) (ws + 0*MB);
  bf16*  woutb = (bf16*) (ws + 13*MB);
  bf16*  wgub  = (bf16*) (ws + 17*MB);
  bf16*  wdnb  = (bf16*) (ws + 29*MB);
  float* xres  = (float*)(ws + 35*MB);
  bf16*  u     = (bf16*) (ws + 43*MB);
  float* dtv   = (float*)(ws + 43*MB);
  float* lav   = (float*)(ws + 43*MB + 256*1024);
  bf16*  hb    = (bf16*) (ws + 43*MB);
  float* zbuf  = (float*)(ws + 47*MB);
  float* x2    = (float*)(ws + 47*MB);
  float* dP    = (float*)(ws + 55*MB);   // two 8MB partials [55,71)
  float* xbcdt = (float*)(ws + 63*MB);
  float* yb    = (float*)(ws + 63*MB);
  float* xbc   = (float*)(ws + 81*MB);
  float* yoP   = (float*)(ws + 81*MB);   // two 8MB partials [81,97)
  float* T     = (float*)(ws + 98*MB);
  bf16*  yn    = (bf16*) (ws + 98*MB);
  float* ctot  = (float*)(ws + 114*MB);

  dim3 blk(256);
  k_cast_all<<<15616, blk, 0, stream>>>(win, wout, wgu, wdn, winb, woutb, wgub, wdnb);
  k_mix_rms<<<LSEQ, blk, 0, stream>>>(x, x0, rm, snw, xres, u);
  k_gemm_inproj<<<dim3(34,16), blk, 0, stream>>>(u, winb, zbuf, xbcdt);
  k_convdt<<<(LSEQ*2208 + 255)/256, blk, 0, stream>>>(xbcdt, cw, cb, dtb, alog, xbc, dtv, lav);
  k_scanA<<<NHEADS*32, blk, 0, stream>>>(xbc, dtv, lav, T, ctot);
  k_scanB<<<NHEADS*8, blk, 0, stream>>>(T, ctot);
  k_scanC<<<NHEADS*32, blk, 0, stream>>>(xbc, T, dtv, lav, Dp, yb);
  k_gate_rms<<<LSEQ, blk, 0, stream>>>(yb, zbuf, mnw, yn);
  k_gemm_splitk<<<dim3(8,16,2), blk, 0, stream>>>(yn, woutb, yoP, DINNER, DINNER/2, DMODEL);
  k_res_rms<<<LSEQ, blk, 0, stream>>>(xres, yoP, yoP + (size_t)LSEQ*DMODEL, sscale, fnw, x2, hb);
  k_gemm_ffn<<<dim3(24,16), blk, 0, stream>>>(hb, wgub, wgub + (size_t)FFNHID*DMODEL, act, DMODEL);
  k_gemm_splitk<<<dim3(8,16,2), blk, 0, stream>>>(act, wdnb, dP, FFNHID, FFNHID/2, DMODEL);
  k_final<<<2048, blk, 0, stream>>>(x2, dP, dP + (size_t)LSEQ*DMODEL, mscale, out);
}

// Round 5
// 258.266 us; speedup vs baseline: 6.3799x; 1.2614x over previous
//
#include <hip/hip_runtime.h>
#include <hip/hip_bf16.h>
#include <math.h>

#define LSEQ 2048
#define DMODEL 1024
#define DINNER 2048
#define NHEADS 32
#define HEADDIM 64
#define DSTATE 64
#define CONVDIM 2176     // DINNER + 2*DSTATE
#define XBCDT_W 2304     // padded width of (xBC | dt) block
#define FFNHID 3072

typedef float f32x4 __attribute__((ext_vector_type(4)));
typedef __bf16 bf16x8 __attribute__((ext_vector_type(8)));
typedef __hip_bfloat16 bf16;

__device__ __forceinline__ float siluf(float x){ return x / (1.0f + expf(-x)); }

// direct global->LDS DMA, 16B per lane; LDS dest is wave-uniform base + lane*16
#define GLOAD_LDS16(gp, lp) __builtin_amdgcn_global_load_lds( \
    (const __attribute__((address_space(1))) void*)(gp), \
    (__attribute__((address_space(3))) void*)(lp), 16, 0, 0)

__device__ __forceinline__ float block_reduce_sum_256(float v){
  #pragma unroll
  for (int o = 32; o > 0; o >>= 1) v += __shfl_down(v, o, 64);
  __shared__ float sh[4];
  int lane = threadIdx.x & 63;
  int w = threadIdx.x >> 6;
  if (lane == 0) sh[w] = v;
  __syncthreads();
  return sh[0] + sh[1] + sh[2] + sh[3];
}

__device__ __forceinline__ ushort bf16bits(float f){
  __hip_bfloat16 h = __float2bfloat16(f);
  return *reinterpret_cast<ushort*>(&h);
}

// XOR-swizzled element index in a 64x64 bf16 LDS tile (8 16B slots/row; slot^=row&7)
__device__ __forceinline__ int swz64(int r, int c){
  return r*64 + ((((c>>3) ^ (r&7)))<<3) + (c&7);
}

// all 4 weight casts in one dispatch, float4 -> 4x bf16 per thread
__global__ __launch_bounds__(256) void k_cast_all(
    const float* __restrict__ w0, const float* __restrict__ w1,
    const float* __restrict__ w2, const float* __restrict__ w3,
    bf16* __restrict__ d0, bf16* __restrict__ d1,
    bf16* __restrict__ d2, bf16* __restrict__ d3)
{
  int idx = blockIdx.x * 256 + threadIdx.x;   // float4 index, total 3997696
  const float* s; bf16* d; int valid;
  if (idx < 1114112)              { s = w0; d = d0; valid = 1089536; }           // winb pad->4352 rows
  else if (idx < 1638400)         { idx -= 1114112; s = w1; d = d1; valid = 524288; }
  else if (idx < 3211264)         { idx -= 1638400; s = w2; d = d2; valid = 1572864; }
  else                            { idx -= 3211264; s = w3; d = d3; valid = 786432; }
  float4 v = (idx < valid) ? *(const float4*)(s + (size_t)idx * 4)
                           : make_float4(0.f, 0.f, 0.f, 0.f);
  ushort4 r;
  r.x = bf16bits(v.x); r.y = bf16bits(v.y); r.z = bf16bits(v.z); r.w = bf16bits(v.w);
  *(ushort4*)(d + (size_t)idx * 4) = r;
}

// x_res = rm0*x + rm1*x0 ; u = bf16(rms(x_res)*ssm_norm_w)
__global__ __launch_bounds__(256) void k_mix_rms(
    const float* __restrict__ x, const float* __restrict__ x0,
    const float* __restrict__ rm, const float* __restrict__ nw,
    float* __restrict__ xres, bf16* __restrict__ u)
{
  int row = blockIdx.x, tid = threadIdx.x;
  float4 xv  = ((const float4*)(x  + (size_t)row * DMODEL))[tid];
  float4 x0v = ((const float4*)(x0 + (size_t)row * DMODEL))[tid];
  float4 r0 = ((const float4*)rm)[tid];
  float4 r1 = ((const float4*)(rm + DMODEL))[tid];
  float4 a;
  a.x = r0.x*xv.x + r1.x*x0v.x; a.y = r0.y*xv.y + r1.y*x0v.y;
  a.z = r0.z*xv.z + r1.z*x0v.z; a.w = r0.w*xv.w + r1.w*x0v.w;
  ((float4*)(xres + (size_t)row * DMODEL))[tid] = a;
  float ss = a.x*a.x + a.y*a.y + a.z*a.z + a.w*a.w;
  ss = block_reduce_sum_256(ss);
  float inv = rsqrtf(ss / (float)DMODEL + 1e-6f);
  float4 nv = ((const float4*)nw)[tid];
  ushort4 o;
  o.x = bf16bits(a.x*inv*nv.x); o.y = bf16bits(a.y*inv*nv.y);
  o.z = bf16bits(a.z*inv*nv.z); o.w = bf16bits(a.w*inv*nv.w);
  *(ushort4*)(u + (size_t)row * DMODEL + tid*4) = o;
}

// ---------- double-buffered bf16 MFMA GEMM mainloop (2-phase prefetch) ----------
__device__ __forceinline__ void gemm_mainloop_db(
    const bf16* __restrict__ A, const bf16* __restrict__ W,
    int ld, int Klen, bf16* As, bf16* Ws, f32x4 acc[4][4])
{
  int tid = threadIdx.x;
  int lane = tid & 63, wid = tid >> 6;
  int wm = (wid >> 1) * 64, wn = (wid & 1) * 64;
  int r16 = lane & 15, g8 = lane >> 4;
  int srow = lane >> 2;
  int scol = ((lane & 3) ^ (srow & 3)) * 8;     // pre-swizzled source slot
  const bf16* ga0 = A + (size_t)(wid*32 + srow) * ld + scol;
  const bf16* ga1 = ga0 + (size_t)16 * ld;
  const bf16* gw0 = W + (size_t)(wid*32 + srow) * ld + scol;
  const bf16* gw1 = gw0 + (size_t)16 * ld;
  bf16* lA = As + wid*1024;
  bf16* lW = Ws + wid*1024;
  GLOAD_LDS16(ga0, lA);
  GLOAD_LDS16(ga1, lA + 512);
  GLOAD_LDS16(gw0, lW);
  GLOAD_LDS16(gw1, lW + 512);
  __syncthreads();
  int cur = 0;
  int s4 = (r16 & 3) * 8;                        // read-side swizzle
  for (int k0 = 0; k0 < Klen; k0 += 32){
    if (k0 + 32 < Klen){
      int nb = (cur ^ 1) * 4096;
      GLOAD_LDS16(ga0 + k0 + 32, As + nb + wid*1024);
      GLOAD_LDS16(ga1 + k0 + 32, As + nb + wid*1024 + 512);
      GLOAD_LDS16(gw0 + k0 + 32, Ws + nb + wid*1024);
      GLOAD_LDS16(gw1 + k0 + 32, Ws + nb + wid*1024 + 512);
    }
    int cb = cur * 4096;
    bf16x8 af[4], bfr[4];
    #pragma unroll
    for (int i = 0; i < 4; ++i)
      af[i] = *(const bf16x8*)(As + cb + (wm + i*16 + r16)*32 + (g8*8 ^ s4));
    #pragma unroll
    for (int j = 0; j < 4; ++j)
      bfr[j] = *(const bf16x8*)(Ws + cb + (wn + j*16 + r16)*32 + (g8*8 ^ s4));
    #pragma unroll
    for (int i = 0; i < 4; ++i)
      #pragma unroll
      for (int j = 0; j < 4; ++j)
        acc[i][j] = __builtin_amdgcn_mfma_f32_16x16x32_bf16(af[i], bfr[j], acc[i][j], 0, 0, 0);
    __syncthreads();
    cur ^= 1;
  }
}

// in_proj: one dispatch, block cols [0,16) -> zbuf (N=2048), [16,34) -> xbcdt (N=2304)
__global__ __launch_bounds__(256) void k_gemm_inproj(
    const bf16* __restrict__ A, const bf16* __restrict__ Wfull,
    float* __restrict__ zbuf, float* __restrict__ xbcdt)
{
  __shared__ __align__(16) bf16 As[2*4096];
  __shared__ __align__(16) bf16 Ws[2*4096];
  int bx = blockIdx.x, by = blockIdx.y;
  f32x4 acc[4][4];
  #pragma unroll
  for (int i = 0; i < 4; ++i)
    #pragma unroll
    for (int j = 0; j < 4; ++j) acc[i][j] = (f32x4){0.f,0.f,0.f,0.f};
  gemm_mainloop_db(A + (size_t)(by*128)*DMODEL, Wfull + (size_t)(bx*128)*DMODEL,
                   DMODEL, DMODEL, As, Ws, acc);
  int tid = threadIdx.x, lane = tid & 63, wid = tid >> 6;
  int wm = (wid >> 1) * 64, wn = (wid & 1) * 64;
  int r16 = lane & 15, g8 = lane >> 4;
  float* Cp; int ldc, col0;
  if (bx < 16){ Cp = zbuf;  ldc = DINNER;  col0 = bx*128; }
  else        { Cp = xbcdt; ldc = XBCDT_W; col0 = (bx-16)*128; }
  #pragma unroll
  for (int i = 0; i < 4; ++i){
    int row = by*128 + wm + i*16 + g8*4;
    #pragma unroll
    for (int j = 0; j < 4; ++j){
      int col = col0 + wn + j*16 + r16;
      #pragma unroll
      for (int r = 0; r < 4; ++r)
        Cp[(size_t)(row + r) * ldc + col] = acc[i][j][r];
    }
  }
}

// split-K GEMM: P[z][M][N] partial over K range [z*Khalf, (z+1)*Khalf)
__global__ __launch_bounds__(256) void k_gemm_splitk(
    const bf16* __restrict__ A, const bf16* __restrict__ W,
    float* __restrict__ P, int Kfull, int Khalf, int N)
{
  __shared__ __align__(16) bf16 As[2*4096];
  __shared__ __align__(16) bf16 Ws[2*4096];
  f32x4 acc[4][4];
  #pragma unroll
  for (int i = 0; i < 4; ++i)
    #pragma unroll
    for (int j = 0; j < 4; ++j) acc[i][j] = (f32x4){0.f,0.f,0.f,0.f};
  int z = blockIdx.z;
  gemm_mainloop_db(A + (size_t)(blockIdx.y*128)*Kfull + z*Khalf,
                   W + (size_t)(blockIdx.x*128)*Kfull + z*Khalf,
                   Kfull, Khalf, As, Ws, acc);
  float* Pz = P + (size_t)z * LSEQ * N;
  int tid = threadIdx.x, lane = tid & 63, wid = tid >> 6;
  int wm = (wid >> 1) * 64, wn = (wid & 1) * 64;
  int r16 = lane & 15, g8 = lane >> 4;
  #pragma unroll
  for (int i = 0; i < 4; ++i){
    int row = blockIdx.y*128 + wm + i*16 + g8*4;
    #pragma unroll
    for (int j = 0; j < 4; ++j){
      int col = blockIdx.x*128 + wn + j*16 + r16;
      #pragma unroll
      for (int r = 0; r < 4; ++r)
        Pz[(size_t)(row + r) * N + col] = acc[i][j][r];
    }
  }
}

// FFN gate_up with fused SwiGLU epilogue: act = bf16(silu(A@Wg^T) * (A@Wu^T))
__global__ __launch_bounds__(256) void k_gemm_ffn(
    const bf16* __restrict__ A, const bf16* __restrict__ Wg, const bf16* __restrict__ Wu,
    bf16* __restrict__ act, int K)
{
  __shared__ __align__(16) bf16 As[2*4096];
  __shared__ __align__(16) bf16 Gs[2*4096];
  __shared__ __align__(16) bf16 Us[2*4096];
  int tid = threadIdx.x;
  int lane = tid & 63, wid = tid >> 6;
  int wm = (wid >> 1) * 64, wn = (wid & 1) * 64;
  int r16 = lane & 15, g8 = lane >> 4;
  int srow = lane >> 2;
  int scol = ((lane & 3) ^ (srow & 3)) * 8;
  const bf16* ga0 = A  + (size_t)(blockIdx.y*128 + wid*32 + srow) * K + scol;
  const bf16* gg0 = Wg + (size_t)(blockIdx.x*128 + wid*32 + srow) * K + scol;
  const bf16* gu0 = Wu + (size_t)(blockIdx.x*128 + wid*32 + srow) * K + scol;
  const bf16* ga1 = ga0 + (size_t)16*K;
  const bf16* gg1 = gg0 + (size_t)16*K;
  const bf16* gu1 = gu0 + (size_t)16*K;
  bf16* lA = As + wid*1024; bf16* lG = Gs + wid*1024; bf16* lU = Us + wid*1024;
  f32x4 accg[4][4], accu[4][4];
  #pragma unroll
  for (int i = 0; i < 4; ++i)
    #pragma unroll
    for (int j = 0; j < 4; ++j){
      accg[i][j] = (f32x4){0.f,0.f,0.f,0.f};
      accu[i][j] = (f32x4){0.f,0.f,0.f,0.f};
    }
  GLOAD_LDS16(ga0, lA); GLOAD_LDS16(ga1, lA + 512);
  GLOAD_LDS16(gg0, lG); GLOAD_LDS16(gg1, lG + 512);
  GLOAD_LDS16(gu0, lU); GLOAD_LDS16(gu1, lU + 512);
  __syncthreads();
  int cur = 0;
  int s4 = (r16 & 3) * 8;
  for (int k0 = 0; k0 < K; k0 += 32){
    if (k0 + 32 < K){
      int nb = (cur ^ 1) * 4096;
      GLOAD_LDS16(ga0 + k0 + 32, As + nb + wid*1024);
      GLOAD_LDS16(ga1 + k0 + 32, As + nb + wid*1024 + 512);
      GLOAD_LDS16(gg0 + k0 + 32, Gs + nb + wid*1024);
      GLOAD_LDS16(gg1 + k0 + 32, Gs + nb + wid*1024 + 512);
      GLOAD_LDS16(gu0 + k0 + 32, Us + nb + wid*1024);
      GLOAD_LDS16(gu1 + k0 + 32, Us + nb + wid*1024 + 512);
    }
    int cb = cur * 4096;
    bf16x8 af[4], gf[4], uf[4];
    #pragma unroll
    for (int i = 0; i < 4; ++i)
      af[i] = *(const bf16x8*)(As + cb + (wm + i*16 + r16)*32 + (g8*8 ^ s4));
    #pragma unroll
    for (int j = 0; j < 4; ++j){
      gf[j] = *(const bf16x8*)(Gs + cb + (wn + j*16 + r16)*32 + (g8*8 ^ s4));
      uf[j] = *(const bf16x8*)(Us + cb + (wn + j*16 + r16)*32 + (g8*8 ^ s4));
    }
    #pragma unroll
    for (int i = 0; i < 4; ++i)
      #pragma unroll
      for (int j = 0; j < 4; ++j){
        accg[i][j] = __builtin_amdgcn_mfma_f32_16x16x32_bf16(af[i], gf[j], accg[i][j], 0, 0, 0);
        accu[i][j] = __builtin_amdgcn_mfma_f32_16x16x32_bf16(af[i], uf[j], accu[i][j], 0, 0, 0);
      }
    __syncthreads();
    cur ^= 1;
  }
  #pragma unroll
  for (int i = 0; i < 4; ++i){
    int row = blockIdx.y*128 + wm + i*16 + g8*4;
    #pragma unroll
    for (int j = 0; j < 4; ++j){
      int col = blockIdx.x*128 + wn + j*16 + r16;
      #pragma unroll
      for (int r = 0; r < 4; ++r){
        float g = accg[i][j][r], u = accu[i][j][r];
        act[(size_t)(row + r) * FFNHID + col] = __float2bfloat16(siluf(g) * u);
      }
    }
  }
}

// fused causal conv4 + bias + silu (cols [0,2176)) and dt/softplus path (cols [2176,2208))
__global__ __launch_bounds__(256) void k_convdt(
    const float* __restrict__ xbcdt, const float* __restrict__ cw,
    const float* __restrict__ cb, const float* __restrict__ dtb,
    const float* __restrict__ alog, float* __restrict__ xbc,
    float* __restrict__ dtv, float* __restrict__ lav)
{
  int idx = blockIdx.x * 256 + threadIdx.x;
  if (idx >= LSEQ * 2208) return;
  int l = idx / 2208, c = idx - l * 2208;
  if (c < CONVDIM){
    float acc = cb[c];
    #pragma unroll
    for (int k = 0; k < 4; ++k){
      int t = l + k - 3;
      if (t >= 0) acc = fmaf(xbcdt[(size_t)t * XBCDT_W + c], cw[c*4 + k], acc);
    }
    xbc[(size_t)l * CONVDIM + c] = siluf(acc);
  } else {
    int h = c - CONVDIM;
    float raw = xbcdt[(size_t)l * XBCDT_W + c] + dtb[h];
    float d = (raw > 20.f) ? raw : log1pf(expf(raw));
    dtv[l * NHEADS + h] = d;
    lav[l * NHEADS + h] = -expf(alog[h]) * d;
  }
}

// ---- MFMA chunked-SSD pass A ----
// T[p][n] = sum_j w_j*dt_j*x[j,p]*B[j,n],  w_j = exp(Lc - cum_j)
__global__ __launch_bounds__(256) void k_scanA(
    const float* __restrict__ xbc, const float* __restrict__ dtv,
    const float* __restrict__ lav, float* __restrict__ T, float* __restrict__ ctot)
{
  __shared__ bf16 sXw[4096];   // [p][j] swizzled, weights folded
  __shared__ bf16 sBt[4096];   // [n][j] swizzled
  __shared__ float scum[64], swt[64];
  int h = blockIdx.x >> 5, c = blockIdx.x & 31;
  int tid = threadIdx.x, t0 = c * 64;
  if (tid < 64){
    float cum = lav[(size_t)(t0 + tid) * NHEADS + h];
    #pragma unroll
    for (int o = 1; o < 64; o <<= 1){
      float v = __shfl_up(cum, o, 64);
      if (tid >= o) cum += v;
    }
    scum[tid] = cum;
  }
  __syncthreads();
  float Lc = scum[63];
  if (tid < 64)
    swt[tid] = expf(Lc - scum[tid]) * dtv[(size_t)(t0 + tid) * NHEADS + h];
  __syncthreads();
  for (int idx = tid; idx < 4096; idx += 256){
    int j = idx >> 6, n = idx & 63;
    size_t rb = (size_t)(t0 + j) * CONVDIM;
    sXw[swz64(n, j)] = __float2bfloat16(xbc[rb + h * HEADDIM + n] * swt[j]);
    sBt[swz64(n, j)] = __float2bfloat16(xbc[rb + DINNER + n]);
  }
  __syncthreads();
  int lane = tid & 63, wid = tid >> 6;
  int wr = (wid >> 1) * 32, wc = (wid & 1) * 32;
  int r16 = lane & 15, g8 = lane >> 4;
  f32x4 acc[2][2];
  #pragma unroll
  for (int i = 0; i < 2; ++i)
    #pragma unroll
    for (int j = 0; j < 2; ++j) acc[i][j] = (f32x4){0.f,0.f,0.f,0.f};
  #pragma unroll
  for (int kk = 0; kk < 2; ++kk){
    int ks = kk*4 + g8;
    bf16x8 a[2], b[2];
    #pragma unroll
    for (int i = 0; i < 2; ++i){
      int row = wr + i*16 + r16;
      a[i] = *(const bf16x8*)(sXw + row*64 + ((ks ^ (row&7))<<3));
    }
    #pragma unroll
    for (int j = 0; j < 2; ++j){
      int row = wc + j*16 + r16;
      b[j] = *(const bf16x8*)(sBt + row*64 + ((ks ^ (row&7))<<3));
    }
    #pragma unroll
    for (int i = 0; i < 2; ++i)
      #pragma unroll
      for (int j = 0; j < 2; ++j)
        acc[i][j] = __builtin_amdgcn_mfma_f32_16x16x32_bf16(a[i], b[j], acc[i][j], 0, 0, 0);
  }
  float* Tb = T + (size_t)blockIdx.x * 4096;
  #pragma unroll
  for (int i = 0; i < 2; ++i)
    #pragma unroll
    for (int j = 0; j < 2; ++j)
      #pragma unroll
      for (int r = 0; r < 4; ++r){
        int p = wr + i*16 + g8*4 + r, n = wc + j*16 + r16;
        Tb[p*64 + n] = acc[i][j][r];
      }
  if (tid == 0) ctot[blockIdx.x] = expf(Lc);
}

// pass B: sequential state recurrence over chunks; stores S_in in place of T
__global__ __launch_bounds__(256) void k_scanB(float* __restrict__ T, const float* __restrict__ ctot)
{
  int h = blockIdx.x >> 3, e = blockIdx.x & 7;
  int tid = threadIdx.x;
  size_t off = (size_t)e * 512 + tid * 2;
  float s0 = 0.f, s1 = 0.f;
  for (int c = 0; c < 32; ++c){
    float ct = ctot[h * 32 + c];
    size_t base = (size_t)(h * 32 + c) * 4096 + off;
    float2 tv = *(const float2*)&T[base];
    *(float2*)&T[base] = make_float2(s0, s1);
    s0 = fmaf(ct, s0, tv.x);
    s1 = fmaf(ct, s1, tv.y);
  }
}

// ---- MFMA chunked-SSD pass C ----
// y[i,p] = sum_{j<=i} G[i,j]*exp(cum_i-cum_j)*dt_j*x[j,p]
//        + exp(cum_i) * sum_n C[i,n]*Sin[p,n] + D*x[i,p]
__global__ __launch_bounds__(256) void k_scanC(
    const float* __restrict__ xbc, const float* __restrict__ Sin,
    const float* __restrict__ dtv, const float* __restrict__ lav,
    const float* __restrict__ Dp, float* __restrict__ y)
{
  __shared__ bf16 sC[4096];    // C [i][n]
  __shared__ bf16 sBS[4096];   // B [j][n]; after G: St [i][j]
  __shared__ bf16 sXt[4096];   // x^T [p][j]
  __shared__ bf16 sXr[4096];   // x [i][p] (for D term)
  __shared__ bf16 sSb[4096];   // Sin [p][n]
  __shared__ float scum[64], sdt[64];
  int h = blockIdx.x >> 5, c = blockIdx.x & 31;
  int tid = threadIdx.x, t0 = c * 64;
  if (tid < 64){
    float cum = lav[(size_t)(t0 + tid) * NHEADS + h];
    #pragma unroll
    for (int o = 1; o < 64; o <<= 1){
      float v = __shfl_up(cum, o, 64);
      if (tid >= o) cum += v;
    }
    scum[tid] = cum;
    sdt[tid] = dtv[(size_t)(t0 + tid) * NHEADS + h];
  }
  for (int idx = tid; idx < 4096; idx += 256){
    int j = idx >> 6, n = idx & 63;
    size_t rb = (size_t)(t0 + j) * CONVDIM;
    float xv = xbc[rb + h * HEADDIM + n];
    sC [swz64(j, n)] = __float2bfloat16(xbc[rb + DINNER + DSTATE + n]);
    sBS[swz64(j, n)] = __float2bfloat16(xbc[rb + DINNER + n]);
    sXr[swz64(j, n)] = __float2bfloat16(xv);
    sXt[swz64(n, j)] = __float2bfloat16(xv);
    sSb[swz64(j, n)] = __float2bfloat16(Sin[(size_t)blockIdx.x * 4096 + idx]);
  }
  __syncthreads();
  int lane = tid & 63, wid = tid >> 6;
  int wr = (wid >> 1) * 32, wc = (wid & 1) * 32;
  int r16 = lane & 15, g8 = lane >> 4;
  // G = C @ B^T  (K = n)
  f32x4 gacc[2][2];
  #pragma unroll
  for (int i = 0; i < 2; ++i)
    #pragma unroll
    for (int j = 0; j < 2; ++j) gacc[i][j] = (f32x4){0.f,0.f,0.f,0.f};
  #pragma unroll
  for (int kk = 0; kk < 2; ++kk){
    int ks = kk*4 + g8;
    bf16x8 a[2], b[2];
    #pragma unroll
    for (int i = 0; i < 2; ++i){
      int row = wr + i*16 + r16;
      a[i] = *(const bf16x8*)(sC + row*64 + ((ks ^ (row&7))<<3));
    }
    #pragma unroll
    for (int j = 0; j < 2; ++j){
      int row = wc + j*16 + r16;
      b[j] = *(const bf16x8*)(sBS + row*64 + ((ks ^ (row&7))<<3));
    }
    #pragma unroll
    for (int i = 0; i < 2; ++i)
      #pragma unroll
      for (int j = 0; j < 2; ++j)
        gacc[i][j] = __builtin_amdgcn_mfma_f32_16x16x32_bf16(a[i], b[j], gacc[i][j], 0, 0, 0);
  }
  __syncthreads();   // B reads done; safe to overwrite with St
  // St[i][j] = (j<=i) ? G * exp(cum_i - cum_j) * dt_j : 0
  #pragma unroll
  for (int i = 0; i < 2; ++i)
    #pragma unroll
    for (int j = 0; j < 2; ++j)
      #pragma unroll
      for (int r = 0; r < 4; ++r){
        int i_ = wr + i*16 + g8*4 + r, j_ = wc + j*16 + r16;
        float v = (j_ <= i_) ? gacc[i][j][r] * expf(scum[i_] - scum[j_]) * sdt[j_] : 0.f;
        sBS[swz64(i_, j_)] = __float2bfloat16(v);
      }
  __syncthreads();
  // acc1 = St @ Xt^T (K=j) ; acc2 = C @ Sb^T (K=n)
  f32x4 a1[2][2], a2[2][2];
  #pragma unroll
  for (int i = 0; i < 2; ++i)
    #pragma unroll
    for (int j = 0; j < 2; ++j){
      a1[i][j] = (f32x4){0.f,0.f,0.f,0.f};
      a2[i][j] = (f32x4){0.f,0.f,0.f,0.f};
    }
  #pragma unroll
  for (int kk = 0; kk < 2; ++kk){
    int ks = kk*4 + g8;
    bf16x8 sa[2], xa[2], ca[2], sb[2];
    #pragma unroll
    for (int i = 0; i < 2; ++i){
      int row = wr + i*16 + r16;
      sa[i] = *(const bf16x8*)(sBS + row*64 + ((ks ^ (row&7))<<3));
      ca[i] = *(const bf16x8*)(sC  + row*64 + ((ks ^ (row&7))<<3));
    }
    #pragma unroll
    for (int j = 0; j < 2; ++j){
      int row = wc + j*16 + r16;
      xa[j] = *(const bf16x8*)(sXt + row*64 + ((ks ^ (row&7))<<3));
      sb[j] = *(const bf16x8*)(sSb + row*64 + ((ks ^ (row&7))<<3));
    }
    #pragma unroll
    for (int i = 0; i < 2; ++i)
      #pragma unroll
      for (int j = 0; j < 2; ++j){
        a1[i][j] = __builtin_amdgcn_mfma_f32_16x16x32_bf16(sa[i], xa[j], a1[i][j], 0, 0, 0);
        a2[i][j] = __builtin_amdgcn_mfma_f32_16x16x32_bf16(ca[i], sb[j], a2[i][j], 0, 0, 0);
      }
  }
  float Dh = Dp[h];
  #pragma unroll
  for (int i = 0; i < 2; ++i)
    #pragma unroll
    for (int r = 0; r < 4; ++r){
      int i_ = wr + i*16 + g8*4 + r;
      float wi = expf(scum[i_]);
      #pragma unroll
      for (int j = 0; j < 2; ++j){
        int p_ = wc + j*16 + r16;
        float xv = __bfloat162float(sXr[swz64(i_, p_)]);
        y[(size_t)(t0 + i_) * DINNER + h * HEADDIM + p_] =
            a1[i][j][r] + wi * a2[i][j][r] + Dh * xv;
      }
    }
}

// yn = bf16(rms(y * silu(z)) * mnorm_w)
__global__ __launch_bounds__(256) void k_gate_rms(
    const float* __restrict__ y, const float* __restrict__ zbuf,
    const float* __restrict__ mw, bf16* __restrict__ yn)
{
  int row = blockIdx.x, tid = threadIdx.x;
  const float4* yr = (const float4*)(y    + (size_t)row * DINNER);
  const float4* zr = (const float4*)(zbuf + (size_t)row * DINNER);
  float4 v[2]; float ss = 0.f;
  #pragma unroll
  for (int i = 0; i < 2; ++i){
    int d4 = tid + i * 256;
    float4 yv = yr[d4], zv = zr[d4];
    float4 g;
    g.x = yv.x * siluf(zv.x); g.y = yv.y * siluf(zv.y);
    g.z = yv.z * siluf(zv.z); g.w = yv.w * siluf(zv.w);
    v[i] = g;
    ss += g.x*g.x + g.y*g.y + g.z*g.z + g.w*g.w;
  }
  ss = block_reduce_sum_256(ss);
  float inv = rsqrtf(ss / (float)DINNER + 1e-6f);
  #pragma unroll
  for (int i = 0; i < 2; ++i){
    int d4 = tid + i * 256;
    float4 mv = ((const float4*)mw)[d4];
    ushort4 o;
    o.x = bf16bits(v[i].x*inv*mv.x); o.y = bf16bits(v[i].y*inv*mv.y);
    o.z = bf16bits(v[i].z*inv*mv.z); o.w = bf16bits(v[i].w*inv*mv.w);
    *(ushort4*)(yn + (size_t)row * DINNER + d4*4) = o;
  }
}

// x2 = xres + ssm_scale*(yo0+yo1) ; hb = bf16(rms(x2)*ffn_norm_w)
__global__ __launch_bounds__(256) void k_res_rms(
    const float* __restrict__ xres, const float* __restrict__ yo0,
    const float* __restrict__ yo1, const float* __restrict__ scale,
    const float* __restrict__ nw, float* __restrict__ x2, bf16* __restrict__ hb)
{
  int row = blockIdx.x, tid = threadIdx.x;
  float4 xv = ((const float4*)(xres + (size_t)row * DMODEL))[tid];
  float4 y0 = ((const float4*)(yo0  + (size_t)row * DMODEL))[tid];
  float4 y1 = ((const float4*)(yo1  + (size_t)row * DMODEL))[tid];
  float4 sv = ((const float4*)scale)[tid];
  float4 a;
  a.x = xv.x + sv.x*(y0.x+y1.x); a.y = xv.y + sv.y*(y0.y+y1.y);
  a.z = xv.z + sv.z*(y0.z+y1.z); a.w = xv.w + sv.w*(y0.w+y1.w);
  ((float4*)(x2 + (size_t)row * DMODEL))[tid] = a;
  float ss = a.x*a.x + a.y*a.y + a.z*a.z + a.w*a.w;
  ss = block_reduce_sum_256(ss);
  float inv = rsqrtf(ss / (float)DMODEL + 1e-6f);
  float4 nv = ((const float4*)nw)[tid];
  ushort4 o;
  o.x = bf16bits(a.x*inv*nv.x); o.y = bf16bits(a.y*inv*nv.y);
  o.z = bf16bits(a.z*inv*nv.z); o.w = bf16bits(a.w*inv*nv.w);
  *(ushort4*)(hb + (size_t)row * DMODEL + tid*4) = o;
}

// out = x2 + mscale*(d0+d1)   (float4)
__global__ __launch_bounds__(256) void k_final(
    const float* __restrict__ x2, const float* __restrict__ d0,
    const float* __restrict__ d1, const float* __restrict__ mscale,
    float* __restrict__ out)
{
  int i4 = blockIdx.x * 256 + threadIdx.x;     // 524288 float4s
  float4 xv = ((const float4*)x2)[i4];
  float4 a  = ((const float4*)d0)[i4];
  float4 b  = ((const float4*)d1)[i4];
  float4 mv = ((const float4*)mscale)[i4 & 255];
  float4 o;
  o.x = xv.x + mv.x*(a.x+b.x); o.y = xv.y + mv.y*(a.y+b.y);
  o.z = xv.z + mv.z*(a.z+b.z); o.w = xv.w + mv.w*(a.w+b.w);
  ((float4*)out)[i4] = o;
}

extern "C" void kernel_launch(void* const* d_in, const int* in_sizes, int n_in,
                              void* d_out, int out_size, void* d_ws, size_t ws_size,
                              hipStream_t stream)
{
  const float* x      = (const float*)d_in[0];
  const float* x0     = (const float*)d_in[1];
  const float* rm     = (const float*)d_in[3];
  const float* sscale = (const float*)d_in[4];
  const float* mscale = (const float*)d_in[5];
  const float* snw    = (const float*)d_in[6];
  const float* fnw    = (const float*)d_in[7];
  const float* win    = (const float*)d_in[8];
  const float* cw     = (const float*)d_in[9];
  const float* cb     = (const float*)d_in[10];
  const float* dtb    = (const float*)d_in[11];
  const float* alog   = (const float*)d_in[12];
  const float* Dp     = (const float*)d_in[13];
  const float* mnw    = (const float*)d_in[14];
  const float* wout   = (const float*)d_in[15];
  const float* wgu    = (const float*)d_in[16];
  const float* wdn    = (const float*)d_in[17];
  float* out = (float*)d_out;

  const size_t MB = 1024ull * 1024ull;
  char* ws = (char*)d_ws;
  bf16*  winb  = (bf16*) (ws + 0*MB);
  bf16*  act   = (bf16*) (ws + 0*MB);
  bf16*  woutb = (bf16*) (ws + 13*MB);
  bf16*  wgub  = (bf16*) (ws + 17*MB);
  bf16*  wdnb  = (bf16*) (ws + 29*MB);
  float* xres  = (float*)(ws + 35*MB);
  bf16*  u     = (bf16*) (ws + 43*MB);
  float* dtv   = (float*)(ws + 43*MB);
  float* lav   = (float*)(ws + 43*MB + 256*1024);
  bf16*  hb    = (bf16*) (ws + 43*MB);
  float* zbuf  = (float*)(ws + 47*MB);
  float* x2    = (float*)(ws + 47*MB);
  float* dP    = (float*)(ws + 55*MB);
  float* xbcdt = (float*)(ws + 63*MB);
  float* yb    = (float*)(ws + 63*MB);
  float* xbc   = (float*)(ws + 81*MB);
  float* yoP   = (float*)(ws + 81*MB);
  float* T     = (float*)(ws + 98*MB);
  bf16*  yn    = (bf16*) (ws + 98*MB);
  float* ctot  = (float*)(ws + 114*MB);

  dim3 blk(256);
  k_cast_all<<<15616, blk, 0, stream>>>(win, wout, wgu, wdn, winb, woutb, wgub, wdnb);
  k_mix_rms<<<LSEQ, blk, 0, stream>>>(x, x0, rm, snw, xres, u);
  k_gemm_inproj<<<dim3(34,16), blk, 0, stream>>>(u, winb, zbuf, xbcdt);
  k_convdt<<<(LSEQ*2208 + 255)/256, blk, 0, stream>>>(xbcdt, cw, cb, dtb, alog, xbc, dtv, lav);
  k_scanA<<<NHEADS*32, blk, 0, stream>>>(xbc, dtv, lav, T, ctot);
  k_scanB<<<NHEADS*8, blk, 0, stream>>>(T, ctot);
  k_scanC<<<NHEADS*32, blk, 0, stream>>>(xbc, T, dtv, lav, Dp, yb);
  k_gate_rms<<<LSEQ, blk, 0, stream>>>(yb, zbuf, mnw, yn);
  k_gemm_splitk<<<dim3(8,16,2), blk, 0, stream>>>(yn, woutb, yoP, DINNER, DINNER/2, DMODEL);
  k_res_rms<<<LSEQ, blk, 0, stream>>>(xres, yoP, yoP + (size_t)LSEQ*DMODEL, sscale, fnw, x2, hb);
  k_gemm_ffn<<<dim3(24,16), blk, 0, stream>>>(hb, wgub, wgub + (size_t)FFNHID*DMODEL, act, DMODEL);
  k_gemm_splitk<<<dim3(8,16,2), blk, 0, stream>>>(act, wdnb, dP, FFNHID, FFNHID/2, DMODEL);
  k_final<<<2048, blk, 0, stream>>>(x2, dP, dP + (size_t)LSEQ*DMODEL, mscale, out);
}

// Round 6
// 223.957 us; speedup vs baseline: 7.3572x; 1.1532x over previous
//
#include <hip/hip_runtime.h>
#include <hip/hip_bf16.h>
#include <math.h>

#define LSEQ 2048
#define DMODEL 1024
#define DINNER 2048
#define NHEADS 32
#define HEADDIM 64
#define DSTATE 64
#define CONVDIM 2176     // DINNER + 2*DSTATE
#define XBCDT_W 2304     // padded width of (xBC | dt) block
#define FFNHID 3072

typedef float f32x4 __attribute__((ext_vector_type(4)));
typedef __bf16 bf16x8 __attribute__((ext_vector_type(8)));
typedef __hip_bfloat16 bf16;

__device__ __forceinline__ float siluf(float x){ return x / (1.0f + expf(-x)); }

#define GLOAD_LDS16(gp, lp) __builtin_amdgcn_global_load_lds( \
    (const __attribute__((address_space(1))) void*)(gp), \
    (__attribute__((address_space(3))) void*)(lp), 16, 0, 0)

__device__ __forceinline__ float block_reduce_sum_256(float v){
  #pragma unroll
  for (int o = 32; o > 0; o >>= 1) v += __shfl_down(v, o, 64);
  __shared__ float sh[4];
  int lane = threadIdx.x & 63;
  int w = threadIdx.x >> 6;
  if (lane == 0) sh[w] = v;
  __syncthreads();
  return sh[0] + sh[1] + sh[2] + sh[3];
}

__device__ __forceinline__ ushort bf16bits(float f){
  __hip_bfloat16 h = __float2bfloat16(f);
  return *reinterpret_cast<ushort*>(&h);
}

// XOR-swizzled element index in a 64x64 bf16 LDS tile (8 16B slots/row; slot^=row&7)
__device__ __forceinline__ int swz64(int r, int c){
  return r*64 + ((((c>>3) ^ (r&7)))<<3) + (c&7);
}

// merged: weight casts (blocks [0,15616)) + mix/rms (blocks [15616,17664))
__global__ __launch_bounds__(256) void k_castmix(
    const float* __restrict__ w0, const float* __restrict__ w1,
    const float* __restrict__ w2, const float* __restrict__ w3,
    bf16* __restrict__ d0, bf16* __restrict__ d1,
    bf16* __restrict__ d2, bf16* __restrict__ d3,
    const float* __restrict__ x, const float* __restrict__ x0,
    const float* __restrict__ rm, const float* __restrict__ nw,
    float* __restrict__ xres, bf16* __restrict__ u)
{
  int tid = threadIdx.x;
  if (blockIdx.x < 15616){
    int idx = blockIdx.x * 256 + tid;   // float4 index
    const float* s; bf16* d; int valid;
    if (idx < 1114112)      { s = w0; d = d0; valid = 1089536; }
    else if (idx < 1638400) { idx -= 1114112; s = w1; d = d1; valid = 524288; }
    else if (idx < 3211264) { idx -= 1638400; s = w2; d = d2; valid = 1572864; }
    else                    { idx -= 3211264; s = w3; d = d3; valid = 786432; }
    float4 v = (idx < valid) ? *(const float4*)(s + (size_t)idx * 4)
                             : make_float4(0.f, 0.f, 0.f, 0.f);
    ushort4 r;
    r.x = bf16bits(v.x); r.y = bf16bits(v.y); r.z = bf16bits(v.z); r.w = bf16bits(v.w);
    *(ushort4*)(d + (size_t)idx * 4) = r;
    return;
  }
  int row = blockIdx.x - 15616;
  float4 xv  = ((const float4*)(x  + (size_t)row * DMODEL))[tid];
  float4 x0v = ((const float4*)(x0 + (size_t)row * DMODEL))[tid];
  float4 r0 = ((const float4*)rm)[tid];
  float4 r1 = ((const float4*)(rm + DMODEL))[tid];
  float4 a;
  a.x = r0.x*xv.x + r1.x*x0v.x; a.y = r0.y*xv.y + r1.y*x0v.y;
  a.z = r0.z*xv.z + r1.z*x0v.z; a.w = r0.w*xv.w + r1.w*x0v.w;
  ((float4*)(xres + (size_t)row * DMODEL))[tid] = a;
  float ss = a.x*a.x + a.y*a.y + a.z*a.z + a.w*a.w;
  ss = block_reduce_sum_256(ss);
  float inv = rsqrtf(ss / (float)DMODEL + 1e-6f);
  float4 nv = ((const float4*)nw)[tid];
  ushort4 o;
  o.x = bf16bits(a.x*inv*nv.x); o.y = bf16bits(a.y*inv*nv.y);
  o.z = bf16bits(a.z*inv*nv.z); o.w = bf16bits(a.w*inv*nv.w);
  *(ushort4*)(u + (size_t)row * DMODEL + tid*4) = o;
}

// ---------- 128M x 64N bf16 MFMA mainloop, double-buffered, BK=32 ----------
// 4 waves (2M x 2N): wave = 64x32 = 4x2 frags of 16x16x32.
// LDS: As[2][128*32] (16KB), Ws[2][64*32] (8KB). gload_lds w=16, XOR-swizzled.
__device__ __forceinline__ void gemm_mainloop64(
    const bf16* __restrict__ A, const bf16* __restrict__ W,
    int ld, int Klen, bf16* As, bf16* Ws, f32x4 acc[4][2])
{
  int tid = threadIdx.x, lane = tid & 63, wid = tid >> 6;
  int wm = (wid >> 1) * 64, wn = (wid & 1) * 32;
  int r16 = lane & 15, g8 = lane >> 4;
  int srow = lane >> 2;
  int scol = ((lane & 3) ^ (srow & 3)) * 8;
  const bf16* ga0 = A + (size_t)(wid*32 + srow) * ld + scol;
  const bf16* ga1 = ga0 + (size_t)16 * ld;
  const bf16* gw0 = W + (size_t)(wid*16 + srow) * ld + scol;
  GLOAD_LDS16(ga0, As + wid*1024);
  GLOAD_LDS16(ga1, As + wid*1024 + 512);
  GLOAD_LDS16(gw0, Ws + wid*512);
  __syncthreads();
  int cur = 0, s4 = (r16 & 3) * 8;
  for (int k0 = 0; k0 < Klen; k0 += 32){
    if (k0 + 32 < Klen){
      GLOAD_LDS16(ga0 + k0 + 32, As + (cur^1)*4096 + wid*1024);
      GLOAD_LDS16(ga1 + k0 + 32, As + (cur^1)*4096 + wid*1024 + 512);
      GLOAD_LDS16(gw0 + k0 + 32, Ws + (cur^1)*2048 + wid*512);
    }
    const bf16* cA = As + cur*4096;
    const bf16* cW = Ws + cur*2048;
    bf16x8 af[4], bfr[2];
    #pragma unroll
    for (int i = 0; i < 4; ++i)
      af[i] = *(const bf16x8*)(cA + (wm + i*16 + r16)*32 + (g8*8 ^ s4));
    #pragma unroll
    for (int j = 0; j < 2; ++j)
      bfr[j] = *(const bf16x8*)(cW + (wn + j*16 + r16)*32 + (g8*8 ^ s4));
    #pragma unroll
    for (int i = 0; i < 4; ++i)
      #pragma unroll
      for (int j = 0; j < 2; ++j)
        acc[i][j] = __builtin_amdgcn_mfma_f32_16x16x32_bf16(af[i], bfr[j], acc[i][j], 0, 0, 0);
    __syncthreads();
    cur ^= 1;
  }
}

// in_proj: block cols [0,32) -> zbuf (N=2048), [32,68) -> xbcdt (N=2304)
__global__ __launch_bounds__(256) void k_gemm_inproj(
    const bf16* __restrict__ A, const bf16* __restrict__ Wfull,
    float* __restrict__ zbuf, float* __restrict__ xbcdt)
{
  __shared__ __align__(16) bf16 As[2*4096];
  __shared__ __align__(16) bf16 Ws[2*2048];
  int bx = blockIdx.x, by = blockIdx.y;
  f32x4 acc[4][2];
  #pragma unroll
  for (int i = 0; i < 4; ++i)
    #pragma unroll
    for (int j = 0; j < 2; ++j) acc[i][j] = (f32x4){0.f,0.f,0.f,0.f};
  gemm_mainloop64(A + (size_t)(by*128)*DMODEL, Wfull + (size_t)(bx*64)*DMODEL,
                  DMODEL, DMODEL, As, Ws, acc);
  int tid = threadIdx.x, lane = tid & 63, wid = tid >> 6;
  int wm = (wid >> 1) * 64, wn = (wid & 1) * 32;
  int r16 = lane & 15, g8 = lane >> 4;
  float* Cp; int ldc, col0;
  if (bx < 32){ Cp = zbuf;  ldc = DINNER;  col0 = bx*64; }
  else        { Cp = xbcdt; ldc = XBCDT_W; col0 = (bx-32)*64; }
  #pragma unroll
  for (int i = 0; i < 4; ++i){
    int row = by*128 + wm + i*16 + g8*4;
    #pragma unroll
    for (int j = 0; j < 2; ++j){
      int col = col0 + wn + j*16 + r16;
      #pragma unroll
      for (int r = 0; r < 4; ++r)
        Cp[(size_t)(row + r) * ldc + col] = acc[i][j][r];
    }
  }
}

// split-K GEMM: P[z][M][N] partial over K range [z*Khalf, (z+1)*Khalf)
__global__ __launch_bounds__(256) void k_gemm_splitk(
    const bf16* __restrict__ A, const bf16* __restrict__ W,
    float* __restrict__ P, int Kfull, int Khalf, int N)
{
  __shared__ __align__(16) bf16 As[2*4096];
  __shared__ __align__(16) bf16 Ws[2*2048];
  f32x4 acc[4][2];
  #pragma unroll
  for (int i = 0; i < 4; ++i)
    #pragma unroll
    for (int j = 0; j < 2; ++j) acc[i][j] = (f32x4){0.f,0.f,0.f,0.f};
  int z = blockIdx.z;
  gemm_mainloop64(A + (size_t)(blockIdx.y*128)*Kfull + z*Khalf,
                  W + (size_t)(blockIdx.x*64)*Kfull + z*Khalf,
                  Kfull, Khalf, As, Ws, acc);
  float* Pz = P + (size_t)z * LSEQ * N;
  int tid = threadIdx.x, lane = tid & 63, wid = tid >> 6;
  int wm = (wid >> 1) * 64, wn = (wid & 1) * 32;
  int r16 = lane & 15, g8 = lane >> 4;
  #pragma unroll
  for (int i = 0; i < 4; ++i){
    int row = blockIdx.y*128 + wm + i*16 + g8*4;
    #pragma unroll
    for (int j = 0; j < 2; ++j){
      int col = blockIdx.x*64 + wn + j*16 + r16;
      #pragma unroll
      for (int r = 0; r < 4; ++r)
        Pz[(size_t)(row + r) * N + col] = acc[i][j][r];
    }
  }
}

// FFN: block computes 128 rows x 64 cols of BOTH gate and up; fused SwiGLU.
__global__ __launch_bounds__(256) void k_gemm_ffn(
    const bf16* __restrict__ A, const bf16* __restrict__ Wg, const bf16* __restrict__ Wu,
    bf16* __restrict__ act, int K)
{
  __shared__ __align__(16) bf16 As[2*4096];
  __shared__ __align__(16) bf16 Gs[2*2048];
  __shared__ __align__(16) bf16 Us[2*2048];
  int tid = threadIdx.x, lane = tid & 63, wid = tid >> 6;
  int wm = (wid >> 1) * 64, wn = (wid & 1) * 32;
  int r16 = lane & 15, g8 = lane >> 4;
  int srow = lane >> 2;
  int scol = ((lane & 3) ^ (srow & 3)) * 8;
  const bf16* ga0 = A  + (size_t)(blockIdx.y*128 + wid*32 + srow) * K + scol;
  const bf16* ga1 = ga0 + (size_t)16*K;
  const bf16* gg0 = Wg + (size_t)(blockIdx.x*64 + wid*16 + srow) * K + scol;
  const bf16* gu0 = Wu + (size_t)(blockIdx.x*64 + wid*16 + srow) * K + scol;
  f32x4 accg[4][2], accu[4][2];
  #pragma unroll
  for (int i = 0; i < 4; ++i)
    #pragma unroll
    for (int j = 0; j < 2; ++j){
      accg[i][j] = (f32x4){0.f,0.f,0.f,0.f};
      accu[i][j] = (f32x4){0.f,0.f,0.f,0.f};
    }
  GLOAD_LDS16(ga0, As + wid*1024);
  GLOAD_LDS16(ga1, As + wid*1024 + 512);
  GLOAD_LDS16(gg0, Gs + wid*512);
  GLOAD_LDS16(gu0, Us + wid*512);
  __syncthreads();
  int cur = 0, s4 = (r16 & 3) * 8;
  for (int k0 = 0; k0 < K; k0 += 32){
    if (k0 + 32 < K){
      GLOAD_LDS16(ga0 + k0 + 32, As + (cur^1)*4096 + wid*1024);
      GLOAD_LDS16(ga1 + k0 + 32, As + (cur^1)*4096 + wid*1024 + 512);
      GLOAD_LDS16(gg0 + k0 + 32, Gs + (cur^1)*2048 + wid*512);
      GLOAD_LDS16(gu0 + k0 + 32, Us + (cur^1)*2048 + wid*512);
    }
    const bf16* cA = As + cur*4096;
    const bf16* cG = Gs + cur*2048;
    const bf16* cU = Us + cur*2048;
    bf16x8 af[4], gf[2], uf[2];
    #pragma unroll
    for (int i = 0; i < 4; ++i)
      af[i] = *(const bf16x8*)(cA + (wm + i*16 + r16)*32 + (g8*8 ^ s4));
    #pragma unroll
    for (int j = 0; j < 2; ++j){
      gf[j] = *(const bf16x8*)(cG + (wn + j*16 + r16)*32 + (g8*8 ^ s4));
      uf[j] = *(const bf16x8*)(cU + (wn + j*16 + r16)*32 + (g8*8 ^ s4));
    }
    #pragma unroll
    for (int i = 0; i < 4; ++i)
      #pragma unroll
      for (int j = 0; j < 2; ++j){
        accg[i][j] = __builtin_amdgcn_mfma_f32_16x16x32_bf16(af[i], gf[j], accg[i][j], 0, 0, 0);
        accu[i][j] = __builtin_amdgcn_mfma_f32_16x16x32_bf16(af[i], uf[j], accu[i][j], 0, 0, 0);
      }
    __syncthreads();
    cur ^= 1;
  }
  #pragma unroll
  for (int i = 0; i < 4; ++i){
    int row = blockIdx.y*128 + wm + i*16 + g8*4;
    #pragma unroll
    for (int j = 0; j < 2; ++j){
      int col = blockIdx.x*64 + wn + j*16 + r16;
      #pragma unroll
      for (int r = 0; r < 4; ++r){
        float g = accg[i][j][r], u = accu[i][j][r];
        act[(size_t)(row + r) * FFNHID + col] = __float2bfloat16(siluf(g) * u);
      }
    }
  }
}

// fused causal conv4 + bias + silu (cols [0,2176)) and dt/softplus path (cols [2176,2208))
__global__ __launch_bounds__(256) void k_convdt(
    const float* __restrict__ xbcdt, const float* __restrict__ cw,
    const float* __restrict__ cb, const float* __restrict__ dtb,
    const float* __restrict__ alog, float* __restrict__ xbc,
    float* __restrict__ dtv, float* __restrict__ lav)
{
  int idx = blockIdx.x * 256 + threadIdx.x;
  if (idx >= LSEQ * 2208) return;
  int l = idx / 2208, c = idx - l * 2208;
  if (c < CONVDIM){
    float acc = cb[c];
    #pragma unroll
    for (int k = 0; k < 4; ++k){
      int t = l + k - 3;
      if (t >= 0) acc = fmaf(xbcdt[(size_t)t * XBCDT_W + c], cw[c*4 + k], acc);
    }
    xbc[(size_t)l * CONVDIM + c] = siluf(acc);
  } else {
    int h = c - CONVDIM;
    float raw = xbcdt[(size_t)l * XBCDT_W + c] + dtb[h];
    float d = (raw > 20.f) ? raw : log1pf(expf(raw));
    dtv[l * NHEADS + h] = d;
    lav[l * NHEADS + h] = -expf(alog[h]) * d;
  }
}

// ---- MFMA chunked-SSD pass A ----
__global__ __launch_bounds__(256) void k_scanA(
    const float* __restrict__ xbc, const float* __restrict__ dtv,
    const float* __restrict__ lav, float* __restrict__ T, float* __restrict__ ctot)
{
  __shared__ bf16 sXw[4096];
  __shared__ bf16 sBt[4096];
  __shared__ float scum[64], swt[64];
  int h = blockIdx.x >> 5, c = blockIdx.x & 31;
  int tid = threadIdx.x, t0 = c * 64;
  if (tid < 64){
    float cum = lav[(size_t)(t0 + tid) * NHEADS + h];
    #pragma unroll
    for (int o = 1; o < 64; o <<= 1){
      float v = __shfl_up(cum, o, 64);
      if (tid >= o) cum += v;
    }
    scum[tid] = cum;
  }
  __syncthreads();
  float Lc = scum[63];
  if (tid < 64)
    swt[tid] = expf(Lc - scum[tid]) * dtv[(size_t)(t0 + tid) * NHEADS + h];
  __syncthreads();
  for (int idx = tid; idx < 4096; idx += 256){
    int j = idx >> 6, n = idx & 63;
    size_t rb = (size_t)(t0 + j) * CONVDIM;
    sXw[swz64(n, j)] = __float2bfloat16(xbc[rb + h * HEADDIM + n] * swt[j]);
    sBt[swz64(n, j)] = __float2bfloat16(xbc[rb + DINNER + n]);
  }
  __syncthreads();
  int lane = tid & 63, wid = tid >> 6;
  int wr = (wid >> 1) * 32, wc = (wid & 1) * 32;
  int r16 = lane & 15, g8 = lane >> 4;
  f32x4 acc[2][2];
  #pragma unroll
  for (int i = 0; i < 2; ++i)
    #pragma unroll
    for (int j = 0; j < 2; ++j) acc[i][j] = (f32x4){0.f,0.f,0.f,0.f};
  #pragma unroll
  for (int kk = 0; kk < 2; ++kk){
    int ks = kk*4 + g8;
    bf16x8 a[2], b[2];
    #pragma unroll
    for (int i = 0; i < 2; ++i){
      int row = wr + i*16 + r16;
      a[i] = *(const bf16x8*)(sXw + row*64 + ((ks ^ (row&7))<<3));
    }
    #pragma unroll
    for (int j = 0; j < 2; ++j){
      int row = wc + j*16 + r16;
      b[j] = *(const bf16x8*)(sBt + row*64 + ((ks ^ (row&7))<<3));
    }
    #pragma unroll
    for (int i = 0; i < 2; ++i)
      #pragma unroll
      for (int j = 0; j < 2; ++j)
        acc[i][j] = __builtin_amdgcn_mfma_f32_16x16x32_bf16(a[i], b[j], acc[i][j], 0, 0, 0);
  }
  float* Tb = T + (size_t)blockIdx.x * 4096;
  #pragma unroll
  for (int i = 0; i < 2; ++i)
    #pragma unroll
    for (int j = 0; j < 2; ++j)
      #pragma unroll
      for (int r = 0; r < 4; ++r){
        int p = wr + i*16 + g8*4 + r, n = wc + j*16 + r16;
        Tb[p*64 + n] = acc[i][j][r];
      }
  if (tid == 0) ctot[blockIdx.x] = expf(Lc);
}

// pass B: sequential state recurrence over chunks; stores S_in in place of T
__global__ __launch_bounds__(256) void k_scanB(float* __restrict__ T, const float* __restrict__ ctot)
{
  int h = blockIdx.x >> 3, e = blockIdx.x & 7;
  int tid = threadIdx.x;
  size_t off = (size_t)e * 512 + tid * 2;
  float s0 = 0.f, s1 = 0.f;
  for (int c = 0; c < 32; ++c){
    float ct = ctot[h * 32 + c];
    size_t base = (size_t)(h * 32 + c) * 4096 + off;
    float2 tv = *(const float2*)&T[base];
    *(float2*)&T[base] = make_float2(s0, s1);
    s0 = fmaf(ct, s0, tv.x);
    s1 = fmaf(ct, s1, tv.y);
  }
}

// ---- MFMA chunked-SSD pass C ----
__global__ __launch_bounds__(256) void k_scanC(
    const float* __restrict__ xbc, const float* __restrict__ Sin,
    const float* __restrict__ dtv, const float* __restrict__ lav,
    const float* __restrict__ Dp, float* __restrict__ y)
{
  __shared__ bf16 sC[4096];
  __shared__ bf16 sBS[4096];
  __shared__ bf16 sXt[4096];
  __shared__ bf16 sXr[4096];
  __shared__ bf16 sSb[4096];
  __shared__ float scum[64], sdt[64];
  int h = blockIdx.x >> 5, c = blockIdx.x & 31;
  int tid = threadIdx.x, t0 = c * 64;
  if (tid < 64){
    float cum = lav[(size_t)(t0 + tid) * NHEADS + h];
    #pragma unroll
    for (int o = 1; o < 64; o <<= 1){
      float v = __shfl_up(cum, o, 64);
      if (tid >= o) cum += v;
    }
    scum[tid] = cum;
    sdt[tid] = dtv[(size_t)(t0 + tid) * NHEADS + h];
  }
  for (int idx = tid; idx < 4096; idx += 256){
    int j = idx >> 6, n = idx & 63;
    size_t rb = (size_t)(t0 + j) * CONVDIM;
    float xv = xbc[rb + h * HEADDIM + n];
    sC [swz64(j, n)] = __float2bfloat16(xbc[rb + DINNER + DSTATE + n]);
    sBS[swz64(j, n)] = __float2bfloat16(xbc[rb + DINNER + n]);
    sXr[swz64(j, n)] = __float2bfloat16(xv);
    sXt[swz64(n, j)] = __float2bfloat16(xv);
    sSb[swz64(j, n)] = __float2bfloat16(Sin[(size_t)blockIdx.x * 4096 + idx]);
  }
  __syncthreads();
  int lane = tid & 63, wid = tid >> 6;
  int wr = (wid >> 1) * 32, wc = (wid & 1) * 32;
  int r16 = lane & 15, g8 = lane >> 4;
  f32x4 gacc[2][2];
  #pragma unroll
  for (int i = 0; i < 2; ++i)
    #pragma unroll
    for (int j = 0; j < 2; ++j) gacc[i][j] = (f32x4){0.f,0.f,0.f,0.f};
  #pragma unroll
  for (int kk = 0; kk < 2; ++kk){
    int ks = kk*4 + g8;
    bf16x8 a[2], b[2];
    #pragma unroll
    for (int i = 0; i < 2; ++i){
      int row = wr + i*16 + r16;
      a[i] = *(const bf16x8*)(sC + row*64 + ((ks ^ (row&7))<<3));
    }
    #pragma unroll
    for (int j = 0; j < 2; ++j){
      int row = wc + j*16 + r16;
      b[j] = *(const bf16x8*)(sBS + row*64 + ((ks ^ (row&7))<<3));
    }
    #pragma unroll
    for (int i = 0; i < 2; ++i)
      #pragma unroll
      for (int j = 0; j < 2; ++j)
        gacc[i][j] = __builtin_amdgcn_mfma_f32_16x16x32_bf16(a[i], b[j], gacc[i][j], 0, 0, 0);
  }
  __syncthreads();
  #pragma unroll
  for (int i = 0; i < 2; ++i)
    #pragma unroll
    for (int j = 0; j < 2; ++j)
      #pragma unroll
      for (int r = 0; r < 4; ++r){
        int i_ = wr + i*16 + g8*4 + r, j_ = wc + j*16 + r16;
        float v = (j_ <= i_) ? gacc[i][j][r] * expf(scum[i_] - scum[j_]) * sdt[j_] : 0.f;
        sBS[swz64(i_, j_)] = __float2bfloat16(v);
      }
  __syncthreads();
  f32x4 a1[2][2], a2[2][2];
  #pragma unroll
  for (int i = 0; i < 2; ++i)
    #pragma unroll
    for (int j = 0; j < 2; ++j){
      a1[i][j] = (f32x4){0.f,0.f,0.f,0.f};
      a2[i][j] = (f32x4){0.f,0.f,0.f,0.f};
    }
  #pragma unroll
  for (int kk = 0; kk < 2; ++kk){
    int ks = kk*4 + g8;
    bf16x8 sa[2], xa[2], ca[2], sb[2];
    #pragma unroll
    for (int i = 0; i < 2; ++i){
      int row = wr + i*16 + r16;
      sa[i] = *(const bf16x8*)(sBS + row*64 + ((ks ^ (row&7))<<3));
      ca[i] = *(const bf16x8*)(sC  + row*64 + ((ks ^ (row&7))<<3));
    }
    #pragma unroll
    for (int j = 0; j < 2; ++j){
      int row = wc + j*16 + r16;
      xa[j] = *(const bf16x8*)(sXt + row*64 + ((ks ^ (row&7))<<3));
      sb[j] = *(const bf16x8*)(sSb + row*64 + ((ks ^ (row&7))<<3));
    }
    #pragma unroll
    for (int i = 0; i < 2; ++i)
      #pragma unroll
      for (int j = 0; j < 2; ++j){
        a1[i][j] = __builtin_amdgcn_mfma_f32_16x16x32_bf16(sa[i], xa[j], a1[i][j], 0, 0, 0);
        a2[i][j] = __builtin_amdgcn_mfma_f32_16x16x32_bf16(ca[i], sb[j], a2[i][j], 0, 0, 0);
      }
  }
  float Dh = Dp[h];
  #pragma unroll
  for (int i = 0; i < 2; ++i)
    #pragma unroll
    for (int r = 0; r < 4; ++r){
      int i_ = wr + i*16 + g8*4 + r;
      float wi = expf(scum[i_]);
      #pragma unroll
      for (int j = 0; j < 2; ++j){
        int p_ = wc + j*16 + r16;
        float xv = __bfloat162float(sXr[swz64(i_, p_)]);
        y[(size_t)(t0 + i_) * DINNER + h * HEADDIM + p_] =
            a1[i][j][r] + wi * a2[i][j][r] + Dh * xv;
      }
    }
}

// yn = bf16(rms(y * silu(z)) * mnorm_w)
__global__ __launch_bounds__(256) void k_gate_rms(
    const float* __restrict__ y, const float* __restrict__ zbuf,
    const float* __restrict__ mw, bf16* __restrict__ yn)
{
  int row = blockIdx.x, tid = threadIdx.x;
  const float4* yr = (const float4*)(y    + (size_t)row * DINNER);
  const float4* zr = (const float4*)(zbuf + (size_t)row * DINNER);
  float4 v[2]; float ss = 0.f;
  #pragma unroll
  for (int i = 0; i < 2; ++i){
    int d4 = tid + i * 256;
    float4 yv = yr[d4], zv = zr[d4];
    float4 g;
    g.x = yv.x * siluf(zv.x); g.y = yv.y * siluf(zv.y);
    g.z = yv.z * siluf(zv.z); g.w = yv.w * siluf(zv.w);
    v[i] = g;
    ss += g.x*g.x + g.y*g.y + g.z*g.z + g.w*g.w;
  }
  ss = block_reduce_sum_256(ss);
  float inv = rsqrtf(ss / (float)DINNER + 1e-6f);
  #pragma unroll
  for (int i = 0; i < 2; ++i){
    int d4 = tid + i * 256;
    float4 mv = ((const float4*)mw)[d4];
    ushort4 o;
    o.x = bf16bits(v[i].x*inv*mv.x); o.y = bf16bits(v[i].y*inv*mv.y);
    o.z = bf16bits(v[i].z*inv*mv.z); o.w = bf16bits(v[i].w*inv*mv.w);
    *(ushort4*)(yn + (size_t)row * DINNER + d4*4) = o;
  }
}

// x2 = xres + ssm_scale*(yo0+yo1) ; hb = bf16(rms(x2)*ffn_norm_w)
__global__ __launch_bounds__(256) void k_res_rms(
    const float* __restrict__ xres, const float* __restrict__ yo0,
    const float* __restrict__ yo1, const float* __restrict__ scale,
    const float* __restrict__ nw, float* __restrict__ x2, bf16* __restrict__ hb)
{
  int row = blockIdx.x, tid = threadIdx.x;
  float4 xv = ((const float4*)(xres + (size_t)row * DMODEL))[tid];
  float4 y0 = ((const float4*)(yo0  + (size_t)row * DMODEL))[tid];
  float4 y1 = ((const float4*)(yo1  + (size_t)row * DMODEL))[tid];
  float4 sv = ((const float4*)scale)[tid];
  float4 a;
  a.x = xv.x + sv.x*(y0.x+y1.x); a.y = xv.y + sv.y*(y0.y+y1.y);
  a.z = xv.z + sv.z*(y0.z+y1.z); a.w = xv.w + sv.w*(y0.w+y1.w);
  ((float4*)(x2 + (size_t)row * DMODEL))[tid] = a;
  float ss = a.x*a.x + a.y*a.y + a.z*a.z + a.w*a.w;
  ss = block_reduce_sum_256(ss);
  float inv = rsqrtf(ss / (float)DMODEL + 1e-6f);
  float4 nv = ((const float4*)nw)[tid];
  ushort4 o;
  o.x = bf16bits(a.x*inv*nv.x); o.y = bf16bits(a.y*inv*nv.y);
  o.z = bf16bits(a.z*inv*nv.z); o.w = bf16bits(a.w*inv*nv.w);
  *(ushort4*)(hb + (size_t)row * DMODEL + tid*4) = o;
}

// out = x2 + mscale*(d0+d1)
__global__ __launch_bounds__(256) void k_final(
    const float* __restrict__ x2, const float* __restrict__ d0,
    const float* __restrict__ d1, const float* __restrict__ mscale,
    float* __restrict__ out)
{
  int i4 = blockIdx.x * 256 + threadIdx.x;
  float4 xv = ((const float4*)x2)[i4];
  float4 a  = ((const float4*)d0)[i4];
  float4 b  = ((const float4*)d1)[i4];
  float4 mv = ((const float4*)mscale)[i4 & 255];
  float4 o;
  o.x = xv.x + mv.x*(a.x+b.x); o.y = xv.y + mv.y*(a.y+b.y);
  o.z = xv.z + mv.z*(a.z+b.z); o.w = xv.w + mv.w*(a.w+b.w);
  ((float4*)out)[i4] = o;
}

extern "C" void kernel_launch(void* const* d_in, const int* in_sizes, int n_in,
                              void* d_out, int out_size, void* d_ws, size_t ws_size,
                              hipStream_t stream)
{
  const float* x      = (const float*)d_in[0];
  const float* x0     = (const float*)d_in[1];
  const float* rm     = (const float*)d_in[3];
  const float* sscale = (const float*)d_in[4];
  const float* mscale = (const float*)d_in[5];
  const float* snw    = (const float*)d_in[6];
  const float* fnw    = (const float*)d_in[7];
  const float* win    = (const float*)d_in[8];
  const float* cw     = (const float*)d_in[9];
  const float* cb     = (const float*)d_in[10];
  const float* dtb    = (const float*)d_in[11];
  const float* alog   = (const float*)d_in[12];
  const float* Dp     = (const float*)d_in[13];
  const float* mnw    = (const float*)d_in[14];
  const float* wout   = (const float*)d_in[15];
  const float* wgu    = (const float*)d_in[16];
  const float* wdn    = (const float*)d_in[17];
  float* out = (float*)d_out;

  const size_t MB = 1024ull * 1024ull;
  char* ws = (char*)d_ws;
  bf16*  winb  = (bf16*) (ws + 0*MB);
  bf16*  act   = (bf16*) (ws + 0*MB);
  bf16*  woutb = (bf16*) (ws + 13*MB);
  bf16*  wgub  = (bf16*) (ws + 17*MB);
  bf16*  wdnb  = (bf16*) (ws + 29*MB);
  float* xres  = (float*)(ws + 35*MB);
  bf16*  u     = (bf16*) (ws + 43*MB);
  float* dtv   = (float*)(ws + 43*MB);
  float* lav   = (float*)(ws + 43*MB + 256*1024);
  bf16*  hb    = (bf16*) (ws + 43*MB);
  float* zbuf  = (float*)(ws + 47*MB);
  float* x2    = (float*)(ws + 47*MB);
  float* dP    = (float*)(ws + 55*MB);
  float* xbcdt = (float*)(ws + 63*MB);
  float* yb    = (float*)(ws + 63*MB);
  float* xbc   = (float*)(ws + 81*MB);
  float* yoP   = (float*)(ws + 81*MB);
  float* T     = (float*)(ws + 98*MB);
  bf16*  yn    = (bf16*) (ws + 98*MB);
  float* ctot  = (float*)(ws + 114*MB);

  dim3 blk(256);
  k_castmix<<<17664, blk, 0, stream>>>(win, wout, wgu, wdn, winb, woutb, wgub, wdnb,
                                       x, x0, rm, snw, xres, u);
  k_gemm_inproj<<<dim3(68,16), blk, 0, stream>>>(u, winb, zbuf, xbcdt);
  k_convdt<<<(LSEQ*2208 + 255)/256, blk, 0, stream>>>(xbcdt, cw, cb, dtb, alog, xbc, dtv, lav);
  k_scanA<<<NHEADS*32, blk, 0, stream>>>(xbc, dtv, lav, T, ctot);
  k_scanB<<<NHEADS*8, blk, 0, stream>>>(T, ctot);
  k_scanC<<<NHEADS*32, blk, 0, stream>>>(xbc, T, dtv, lav, Dp, yb);
  k_gate_rms<<<LSEQ, blk, 0, stream>>>(yb, zbuf, mnw, yn);
  k_gemm_splitk<<<dim3(16,16,2), blk, 0, stream>>>(yn, woutb, yoP, DINNER, DINNER/2, DMODEL);
  k_res_rms<<<LSEQ, blk, 0, stream>>>(xres, yoP, yoP + (size_t)LSEQ*DMODEL, sscale, fnw, x2, hb);
  k_gemm_ffn<<<dim3(48,16), blk, 0, stream>>>(hb, wgub, wgub + (size_t)FFNHID*DMODEL, act, DMODEL);
  k_gemm_splitk<<<dim3(16,16,2), blk, 0, stream>>>(act, wdnb, dP, FFNHID, FFNHID/2, DMODEL);
  k_final<<<2048, blk, 0, stream>>>(x2, dP, dP + (size_t)LSEQ*DMODEL, mscale, out);
}